// Round 16
// baseline (1783.837 us; speedup 1.0000x reference)
//
#include <hip/hip_runtime.h>
#include <hip/hip_cooperative_groups.h>
#include <math.h>

namespace cg = cooperative_groups;

#define HDIM 128
#define NGAUSS 50
#define NLAYER 6
#define TSTR 136   // LDS bf16 tile row stride (shorts)
#define VSTR 132   // LDS f32 tile row stride (floats)
#define DINV (1.0f/512.0f)
#define COOPG 256  // cooperative grid: 256 blocks x 512 threads = 1 block/CU

typedef unsigned short ushortT;
typedef __attribute__((ext_vector_type(8))) short bf16x8;
typedef __attribute__((ext_vector_type(4))) float f32x4;

static __device__ __forceinline__ float bf2f(unsigned short u){
  union { unsigned int i; float f; } x; x.i = ((unsigned int)u) << 16; return x.f;
}
static __device__ __forceinline__ unsigned short f2bf(float f){
  union { float f; unsigned int i; } x; x.f = f;
  unsigned int i = x.i;
  unsigned int r = (i + 0x7FFFu + ((i >> 16) & 1u)) >> 16;
  return (unsigned short)r;
}
static __device__ __forceinline__ float ssp(float x){
  return fmaxf(x, 0.0f) + __logf(1.0f + __expf(-fabsf(x))) - 0.69314718055994530942f;
}
static __device__ __forceinline__ f32x4 mfma4r(const bf16x8* a, const bf16x8* b){
  f32x4 d = {0.f, 0.f, 0.f, 0.f};
  d = __builtin_amdgcn_mfma_f32_16x16x32_bf16(a[0], b[0], d, 0, 0, 0);
  d = __builtin_amdgcn_mfma_f32_16x16x32_bf16(a[1], b[1], d, 0, 0, 0);
  d = __builtin_amdgcn_mfma_f32_16x16x32_bf16(a[2], b[2], d, 0, 0, 0);
  d = __builtin_amdgcn_mfma_f32_16x16x32_bf16(a[3], b[3], d, 0, 0, 0);
  return d;
}

struct MegaP {
  const int* z; const float* pos; const int* batch; const int* erow; const int* ecol;
  const float* emb; const float* dW; const float* db; const float* Wn;
  const float* We; const float* be; const float* Wo; const float* bo;
  const float* W1; const float* b1; const float* W2; const float* b2;
  int* counts; int* offsets; int* cursor; int* partials;
  unsigned int* csr; ushortT* h0; ushortT* h1; ushortT* vhi; ushortT* agg;
  ushortT* WnT; ushortT* WoT; float* a; float* c; float* u; int* groupOff;
  float* out;
  int N, E, G;
};

// ================= cooperative mega-kernel =================
__global__ __launch_bounds__(512, 2)
void k_mega(MegaP p){
  cg::grid_group grid = cg::this_grid();
  __shared__ char smbytes[16 * VSTR * 4];   // 8448 B, reused per phase
  int*     s_scan = (int*)smbytes;
  ushortT* s_vh   = (ushortT*)smbytes;
  float*   s_vf   = (float*)smbytes;

  int tid = threadIdx.x;
  int wave = tid >> 6, lane = tid & 63;
  int m = lane & 15, quad = lane >> 4;
  int gsz = gridDim.x;
  int gthreads = gsz * 512;
  int gtid = blockIdx.x * 512 + tid;
  int gwave = blockIdx.x * 8 + wave;
  int gwaves = gsz * 8;
  int ntiles = (p.N + 15) >> 4;

  // ---- phase 0: setup
  for (int i = gtid; i < p.N; i += gthreads) p.counts[i] = 0;
  for (int i = gtid; i < p.N * HDIM; i += gthreads){
    int n = i >> 7, f = i & 127;
    p.vhi[i] = f2bf(p.emb[p.z[n] * HDIM + f]);
  }
  for (int i = gtid; i < NLAYER * HDIM * HDIM; i += gthreads){
    int mat = i >> 14, rem = i & 16383;
    int n = rem >> 7, k = rem & 127;
    p.WnT[i] = f2bf(p.Wn[(mat << 14) + k * HDIM + n]);
    p.WoT[i] = f2bf(p.Wo[(mat << 14) + k * HDIM + n]);
  }
  for (int i = gtid; i < NLAYER * HDIM; i += gthreads){
    int l = i >> 7, f = i & 127;
    float av = 0.f, cv = 0.f;
    for (int g = 0; g < NGAUSS; ++g){
      float we = p.We[(l * NGAUSS + g) * HDIM + f];
      av += p.dW[g] * we;
      cv += p.db[g] * we;
    }
    p.a[i] = av; p.c[i] = cv + p.be[i];
  }
  for (int i = gtid; i < p.N; i += gthreads){
    int bb = p.batch[i];
    if (i == 0){ for (int g = 0; g <= bb; ++g) p.groupOff[g] = 0; }
    else { int pb = p.batch[i - 1]; for (int g = pb + 1; g <= bb; ++g) p.groupOff[g] = i; }
    if (i == p.N - 1){ for (int g = bb + 1; g <= p.G; ++g) p.groupOff[g] = p.N; }
  }
  grid.sync();

  // ---- phase 1: degree count + gemm0
  for (int e = gtid; e < p.E; e += gthreads) atomicAdd(&p.counts[p.erow[e]], 1);
  for (int job = gwave; job < ntiles * 8; job += gwaves){
    int tile = job >> 3, ct = job & 7;
    int rowBase = tile << 4;
    int row = rowBase + m; if (row >= p.N) row = p.N - 1;
    bf16x8 av[4];
    #pragma unroll
    for (int kk = 0; kk < 4; ++kk)
      av[kk] = *(const bf16x8*)(p.vhi + ((size_t)row << 7) + kk*32 + quad*8);
    int ncol = ct * 16 + m;
    const ushortT* bp = p.WnT + ((size_t)ncol << 7) + quad*8;
    bf16x8 bb[4];
    #pragma unroll
    for (int kk = 0; kk < 4; ++kk) bb[kk] = *(const bf16x8*)(bp + kk*32);
    f32x4 d = mfma4r(av, bb);
    #pragma unroll
    for (int r = 0; r < 4; ++r){
      int orow = rowBase + quad*4 + r;
      if (orow < p.N) p.h0[((size_t)orow << 7) + ncol] = f2bf(d[r]);
    }
  }
  grid.sync();

  // ---- scan A: per-block chunk sums (chunk = 196 <= 512)
  int chunk = (p.N + gsz - 1) / gsz;
  {
    int idx = blockIdx.x * chunk + tid;
    int v = (tid < chunk && idx < p.N) ? p.counts[idx] : 0;
    s_scan[tid] = v;
    __syncthreads();
    #pragma unroll
    for (int off = 256; off > 0; off >>= 1){
      if (tid < off) s_scan[tid] += s_scan[tid + off];
      __syncthreads();
    }
    if (tid == 0) p.partials[blockIdx.x] = s_scan[0];
  }
  grid.sync();
  // ---- scan B
  if (blockIdx.x == 0){
    int v = (tid < gsz) ? p.partials[tid] : 0;
    s_scan[tid] = v;
    __syncthreads();
    for (int off = 1; off < 512; off <<= 1){
      int t = (tid >= off) ? s_scan[tid - off] : 0;
      __syncthreads();
      s_scan[tid] += t;
      __syncthreads();
    }
    if (tid < gsz) p.partials[tid] = s_scan[tid] - v;
  }
  grid.sync();
  // ---- scan C
  {
    int idx = blockIdx.x * chunk + tid;
    int v = (tid < chunk && idx < p.N) ? p.counts[idx] : 0;
    s_scan[tid] = v;
    __syncthreads();
    for (int off = 1; off < 512; off <<= 1){
      int t = (tid >= off) ? s_scan[tid - off] : 0;
      __syncthreads();
      s_scan[tid] += t;
      __syncthreads();
    }
    int excl = p.partials[blockIdx.x] + s_scan[tid] - v;
    if (tid < chunk && idx < p.N){
      p.offsets[idx] = excl; p.cursor[idx] = excl;
      if (idx == p.N - 1) p.offsets[p.N] = excl + v;
    }
  }
  grid.sync();
  // ---- fill
  for (int e = gtid; e < p.E; e += gthreads){
    int r = p.erow[e], cc = p.ecol[e];
    float dx = p.pos[r*3+0] - p.pos[cc*3+0];
    float dy = p.pos[r*3+1] - p.pos[cc*3+1];
    float dz = p.pos[r*3+2] - p.pos[cc*3+2];
    float d = sqrtf(dx*dx + dy*dy + dz*dz);
    int du = (int)(d * 512.0f + 0.5f);
    if (du > 65535) du = 65535;
    int slot = atomicAdd(&p.cursor[r], 1);
    p.csr[slot] = ((unsigned int)cc << 16) | (unsigned int)du;
  }
  grid.sync();

  // ---- layers
  for (int l = 0; l < NLAYER; ++l){
    const ushortT* hin  = (l & 1) ? p.h1 : p.h0;
    ushortT*       hout = (l & 1) ? p.h0 : p.h1;
    const float* al = p.a + l * HDIM;
    const float* cl = p.c + l * HDIM;
    {
      int half = lane >> 5;
      int fl = (lane & 31) * 4;
      float4 av4 = *(const float4*)(al + fl);
      float4 cv4 = *(const float4*)(cl + fl);
      for (int node = gwave; node < p.N; node += gwaves){
        int s = p.offsets[node], e = p.offsets[node + 1];
        float acc0 = 0.f, acc1 = 0.f, acc2 = 0.f, acc3 = 0.f;
        int j = s;
        for (; j + 8 <= e; j += 8){
          unsigned int q[4]; uint2 pp[4];
          #pragma unroll
          for (int i = 0; i < 4; ++i) q[i] = p.csr[j + 2*i + half];
          #pragma unroll
          for (int i = 0; i < 4; ++i)
            pp[i] = *(const uint2*)(hin + ((size_t)(q[i] >> 16) << 7) + fl);
          #pragma unroll
          for (int i = 0; i < 4; ++i){
            float dd = (float)(q[i] & 0xFFFFu) * DINV;
            acc0 = fmaf(bf2f((ushortT)pp[i].x),         fmaf(dd, av4.x, cv4.x), acc0);
            acc1 = fmaf(bf2f((ushortT)(pp[i].x >> 16)), fmaf(dd, av4.y, cv4.y), acc1);
            acc2 = fmaf(bf2f((ushortT)pp[i].y),         fmaf(dd, av4.z, cv4.z), acc2);
            acc3 = fmaf(bf2f((ushortT)(pp[i].y >> 16)), fmaf(dd, av4.w, cv4.w), acc3);
          }
        }
        for (; j < e; j += 2){
          int myj = j + half;
          if (myj < e){
            unsigned int q = p.csr[myj];
            uint2 pp = *(const uint2*)(hin + ((size_t)(q >> 16) << 7) + fl);
            float dd = (float)(q & 0xFFFFu) * DINV;
            acc0 = fmaf(bf2f((ushortT)pp.x),         fmaf(dd, av4.x, cv4.x), acc0);
            acc1 = fmaf(bf2f((ushortT)(pp.x >> 16)), fmaf(dd, av4.y, cv4.y), acc1);
            acc2 = fmaf(bf2f((ushortT)pp.y),         fmaf(dd, av4.z, cv4.z), acc2);
            acc3 = fmaf(bf2f((ushortT)(pp.y >> 16)), fmaf(dd, av4.w, cv4.w), acc3);
          }
        }
        acc0 += __shfl_down(acc0, 32, 64);
        acc1 += __shfl_down(acc1, 32, 64);
        acc2 += __shfl_down(acc2, 32, 64);
        acc3 += __shfl_down(acc3, 32, 64);
        if (half == 0){
          uint2 ph;
          ph.x = (unsigned int)f2bf(acc0) | ((unsigned int)f2bf(acc1) << 16);
          ph.y = (unsigned int)f2bf(acc2) | ((unsigned int)f2bf(acc3) << 16);
          *(uint2*)(p.agg + ((size_t)node << 7) + fl) = ph;
        }
      }
    }
    grid.sync();
    const ushortT* WoTl = p.WoT + (size_t)l * HDIM * HDIM;
    const float*   bol  = p.bo + (size_t)l * HDIM;
    int ncol = wave * 16 + m;
    if (l < NLAYER - 1){
      const ushortT* WnTn = p.WnT + (size_t)(l + 1) * HDIM * HDIM;
      for (int tile = blockIdx.x; tile < ntiles; tile += gsz){
        int rowBase = tile << 4;
        int row = rowBase + m; if (row >= p.N) row = p.N - 1;
        bf16x8 b2f[4];
        const ushortT* bp2 = WnTn + ((size_t)ncol << 7) + quad*8;
        #pragma unroll
        for (int kk = 0; kk < 4; ++kk) b2f[kk] = *(const bf16x8*)(bp2 + kk*32);
        bf16x8 av[4];
        #pragma unroll
        for (int kk = 0; kk < 4; ++kk)
          av[kk] = *(const bf16x8*)(p.agg + ((size_t)row << 7) + kk*32 + quad*8);
        const ushortT* bp = WoTl + ((size_t)ncol << 7) + quad*8;
        bf16x8 bb[4];
        #pragma unroll
        for (int kk = 0; kk < 4; ++kk) bb[kk] = *(const bf16x8*)(bp + kk*32);
        f32x4 d = mfma4r(av, bb);
        float bbias = bol[ncol];
        #pragma unroll
        for (int r = 0; r < 4; ++r)
          s_vh[(quad*4 + r) * TSTR + ncol] = f2bf(ssp(d[r] + bbias));
        __syncthreads();
        bf16x8 a2[4];
        #pragma unroll
        for (int kk = 0; kk < 4; ++kk)
          a2[kk] = *(const bf16x8*)(&s_vh[m * TSTR + kk*32 + quad*8]);
        f32x4 d2 = mfma4r(a2, b2f);
        #pragma unroll
        for (int r = 0; r < 4; ++r){
          int orow = rowBase + quad*4 + r;
          if (orow < p.N) hout[((size_t)orow << 7) + ncol] = f2bf(d2[r]);
        }
        __syncthreads();
      }
    } else {
      for (int tile = blockIdx.x; tile < ntiles; tile += gsz){
        int rowBase = tile << 4;
        int row = rowBase + m; if (row >= p.N) row = p.N - 1;
        bf16x8 av[4];
        #pragma unroll
        for (int kk = 0; kk < 4; ++kk)
          av[kk] = *(const bf16x8*)(p.agg + ((size_t)row << 7) + kk*32 + quad*8);
        const ushortT* bp = WoTl + ((size_t)ncol << 7) + quad*8;
        bf16x8 bb[4];
        #pragma unroll
        for (int kk = 0; kk < 4; ++kk) bb[kk] = *(const bf16x8*)(bp + kk*32);
        f32x4 d = mfma4r(av, bb);
        float bbias = bol[ncol];
        #pragma unroll
        for (int r = 0; r < 4; ++r)
          s_vf[(quad*4 + r) * VSTR + ncol] = ssp(d[r] + bbias);
        __syncthreads();
        #pragma unroll 1
        for (int i = 0; i < 2; ++i){
          int node = rowBase + wave*2 + i;
          if (node < p.N){
            const float* vrow = &s_vf[(wave*2 + i) * VSTR];
            float tt0 = p.b1[lane], tt1 = 0.f;
            #pragma unroll 8
            for (int k = 0; k < HDIM; k += 2){
              tt0 = fmaf(vrow[k],     p.W1[k * 64 + lane],       tt0);
              tt1 = fmaf(vrow[k + 1], p.W1[(k + 1) * 64 + lane], tt1);
            }
            float partial = ssp(tt0 + tt1) * p.W2[lane];
            #pragma unroll
            for (int off = 32; off > 0; off >>= 1)
              partial += __shfl_down(partial, off, 64);
            if (lane == 0) p.u[node] = partial + p.b2[0];
          }
        }
        __syncthreads();
      }
    }
    grid.sync();
  }

  // ---- gsum
  for (int g = gwave; g < p.G; g += gwaves){
    int s = p.groupOff[g], e = p.groupOff[g + 1];
    float acc = 0.f;
    for (int j = s + lane; j < e; j += 64) acc += p.u[j];
    #pragma unroll
    for (int off = 32; off > 0; off >>= 1)
      acc += __shfl_down(acc, off, 64);
    if (lane == 0) p.out[g] = acc;
  }
}

// ================= fallback kernels (R14, known-good 848us) =================
__global__ void k_count(const int* __restrict__ row, int* __restrict__ counts, int E){
  int e = blockIdx.x * 256 + threadIdx.x;
  if (e < E) atomicAdd(&counts[row[e]], 1);
}

__global__ void k_scan1(const int* __restrict__ counts, int* __restrict__ blockSums, int N){
  __shared__ int red[256];
  int tid = threadIdx.x;
  int i = blockIdx.x * 256 + tid;
  red[tid] = (i < N) ? counts[i] : 0;
  __syncthreads();
  #pragma unroll
  for (int off = 128; off > 0; off >>= 1){
    if (tid < off) red[tid] += red[tid + off];
    __syncthreads();
  }
  if (tid == 0) blockSums[blockIdx.x] = red[0];
}

__global__ void k_scan3(const int* __restrict__ counts, const int* __restrict__ blockSums,
                        int* __restrict__ offsets, int* __restrict__ cursor, int N, int nb){
  __shared__ int bs[256];
  __shared__ int s[256];
  int tid = threadIdx.x;
  bs[tid] = (tid < nb) ? blockSums[tid] : 0;
  __syncthreads();
  #pragma unroll
  for (int off = 1; off < 256; off <<= 1){
    int t = (tid >= off) ? bs[tid - off] : 0;
    __syncthreads();
    bs[tid] += t;
    __syncthreads();
  }
  int myOff = (blockIdx.x == 0) ? 0 : bs[blockIdx.x - 1];
  int i = blockIdx.x * 256 + tid;
  int v = (i < N) ? counts[i] : 0;
  s[tid] = v;
  __syncthreads();
  #pragma unroll
  for (int off = 1; off < 256; off <<= 1){
    int t = (tid >= off) ? s[tid - off] : 0;
    __syncthreads();
    s[tid] += t;
    __syncthreads();
  }
  int excl = myOff + s[tid] - v;
  if (i < N){ offsets[i] = excl; cursor[i] = excl; }
  if (i == N - 1) offsets[N] = excl + v;
}

__global__ void k_fill(const int* __restrict__ row, const int* __restrict__ col,
                       const float* __restrict__ pos, int* __restrict__ cursor,
                       unsigned int* __restrict__ csr, int E){
  int e = blockIdx.x * 256 + threadIdx.x;
  if (e >= E) return;
  int r = row[e], c = col[e];
  float dx = pos[r*3+0] - pos[c*3+0];
  float dy = pos[r*3+1] - pos[c*3+1];
  float dz = pos[r*3+2] - pos[c*3+2];
  float d = sqrtf(dx*dx + dy*dy + dz*dz);
  int du = (int)(d * 512.0f + 0.5f);
  if (du > 65535) du = 65535;
  int slot = atomicAdd(&cursor[r], 1);
  csr[slot] = ((unsigned int)c << 16) | (unsigned int)du;
}

__global__ void k_setup(const int* __restrict__ z, const float* __restrict__ emb,
                        ushortT* __restrict__ vhi,
                        const float* __restrict__ Wn, ushortT* __restrict__ WnT,
                        const float* __restrict__ Wo, ushortT* __restrict__ WoT,
                        const float* __restrict__ dW, const float* __restrict__ db,
                        const float* __restrict__ We, const float* __restrict__ be,
                        float* __restrict__ a, float* __restrict__ c,
                        const int* __restrict__ batch, int* __restrict__ groupOff,
                        int* __restrict__ counts,
                        int N, int G, int B0, int B1, int B2, int B4, int B5){
  int b = blockIdx.x;
  int tid = threadIdx.x;
  if (b < B0){
    int i = b * 256 + tid;
    if (i < N) counts[i] = 0;
    return;
  }
  b -= B0;
  if (b < B1){
    int idx = b * 256 + tid;
    if (idx < N * HDIM){
      int n = idx >> 7, f = idx & 127;
      vhi[idx] = f2bf(emb[z[n] * HDIM + f]);
    }
    return;
  }
  b -= B1;
  if (b < B2){
    int idx = b * 256 + tid;
    if (idx < NLAYER * HDIM * HDIM){
      int mat = idx >> 14, rem = idx & 16383;
      int n = rem >> 7, k = rem & 127;
      WnT[idx] = f2bf(Wn[(mat << 14) + k * HDIM + n]);
    }
    return;
  }
  b -= B2;
  if (b < B2){
    int idx = b * 256 + tid;
    if (idx < NLAYER * HDIM * HDIM){
      int mat = idx >> 14, rem = idx & 16383;
      int n = rem >> 7, k = rem & 127;
      WoT[idx] = f2bf(Wo[(mat << 14) + k * HDIM + n]);
    }
    return;
  }
  b -= B2;
  if (b < B4){
    int idx = b * 256 + tid;
    if (idx < NLAYER * HDIM){
      int l = idx >> 7, f = idx & 127;
      float av = 0.f, cv = 0.f;
      for (int g = 0; g < NGAUSS; ++g){
        float we = We[(l * NGAUSS + g) * HDIM + f];
        av += dW[g] * we;
        cv += db[g] * we;
      }
      a[idx] = av;
      c[idx] = cv + be[idx];
    }
    return;
  }
  b -= B4;
  if (b < B5){
    int i = b * 256 + tid;
    if (i >= N) return;
    int bb = batch[i];
    if (i == 0){
      for (int g = 0; g <= bb; ++g) groupOff[g] = 0;
    } else {
      int pb = batch[i - 1];
      for (int g = pb + 1; g <= bb; ++g) groupOff[g] = i;
    }
    if (i == N - 1){
      for (int g = bb + 1; g <= G; ++g) groupOff[g] = N;
    }
  }
}

__global__ __launch_bounds__(128, 2)
void k_gemm0(const ushortT* __restrict__ X, const ushortT* __restrict__ WT,
             ushortT* __restrict__ outHi, int N){
  int tid = threadIdx.x;
  int wave = tid >> 6, lane = tid & 63;
  int m = lane & 15, quad = lane >> 4;
  int ntiles = (N + 15) >> 4;
  int t0 = (blockIdx.x * 2 + wave) * 2;
  if (t0 >= ntiles) return;

  bf16x8 av[2][4];
  #pragma unroll
  for (int rt = 0; rt < 2; ++rt){
    int row = (t0 + rt) * 16 + m; if (row >= N) row = N - 1;
    #pragma unroll
    for (int kk = 0; kk < 4; ++kk)
      av[rt][kk] = *(const bf16x8*)(X + ((size_t)row << 7) + kk*32 + quad*8);
  }
  #pragma unroll
  for (int ct = 0; ct < 8; ++ct){
    int ncol = ct * 16 + m;
    const ushortT* bp = WT + ((size_t)ncol << 7) + quad*8;
    bf16x8 bb[4];
    #pragma unroll
    for (int kk = 0; kk < 4; ++kk) bb[kk] = *(const bf16x8*)(bp + kk*32);
    #pragma unroll
    for (int rt = 0; rt < 2; ++rt){
      f32x4 d = mfma4r(av[rt], bb);
      #pragma unroll
      for (int r = 0; r < 4; ++r){
        int orow = (t0 + rt) * 16 + quad*4 + r;
        if (orow < N) outHi[((size_t)orow << 7) + ncol] = f2bf(d[r]);
      }
    }
  }
}

__global__ __launch_bounds__(256, 8)
void k_agg2(const ushortT* __restrict__ h, const int* __restrict__ offsets,
            const unsigned int* __restrict__ cd, const float* __restrict__ a,
            const float* __restrict__ c, ushortT* __restrict__ aggHi, int N){
  int node = blockIdx.x * 4 + (threadIdx.x >> 6);
  if (node >= N) return;
  int lane = threadIdx.x & 63;
  int half = lane >> 5;
  int fl = (lane & 31) * 4;
  float4 av = *(const float4*)(a + fl);
  float4 cv = *(const float4*)(c + fl);
  int s = offsets[node], e = offsets[node + 1];
  float acc0 = 0.f, acc1 = 0.f, acc2 = 0.f, acc3 = 0.f;
  int j = s;
  for (; j + 8 <= e; j += 8){
    unsigned int q[4]; uint2 p[4];
    #pragma unroll
    for (int i = 0; i < 4; ++i) q[i] = cd[j + 2*i + half];
    #pragma unroll
    for (int i = 0; i < 4; ++i)
      p[i] = *(const uint2*)(h + ((size_t)(q[i] >> 16) << 7) + fl);
    #pragma unroll
    for (int i = 0; i < 4; ++i){
      float dd = (float)(q[i] & 0xFFFFu) * DINV;
      acc0 = fmaf(bf2f((ushortT)p[i].x),         fmaf(dd, av.x, cv.x), acc0);
      acc1 = fmaf(bf2f((ushortT)(p[i].x >> 16)), fmaf(dd, av.y, cv.y), acc1);
      acc2 = fmaf(bf2f((ushortT)p[i].y),         fmaf(dd, av.z, cv.z), acc2);
      acc3 = fmaf(bf2f((ushortT)(p[i].y >> 16)), fmaf(dd, av.w, cv.w), acc3);
    }
  }
  for (; j < e; j += 2){
    int myj = j + half;
    if (myj < e){
      unsigned int q = cd[myj];
      uint2 p = *(const uint2*)(h + ((size_t)(q >> 16) << 7) + fl);
      float dd = (float)(q & 0xFFFFu) * DINV;
      acc0 = fmaf(bf2f((ushortT)p.x),         fmaf(dd, av.x, cv.x), acc0);
      acc1 = fmaf(bf2f((ushortT)(p.x >> 16)), fmaf(dd, av.y, cv.y), acc1);
      acc2 = fmaf(bf2f((ushortT)p.y),         fmaf(dd, av.z, cv.z), acc2);
      acc3 = fmaf(bf2f((ushortT)(p.y >> 16)), fmaf(dd, av.w, cv.w), acc3);
    }
  }
  acc0 += __shfl_down(acc0, 32, 64);
  acc1 += __shfl_down(acc1, 32, 64);
  acc2 += __shfl_down(acc2, 32, 64);
  acc3 += __shfl_down(acc3, 32, 64);
  if (half == 0){
    uint2 ph;
    ph.x = (unsigned int)f2bf(acc0) | ((unsigned int)f2bf(acc1) << 16);
    ph.y = (unsigned int)f2bf(acc2) | ((unsigned int)f2bf(acc3) << 16);
    *(uint2*)(aggHi + ((size_t)node << 7) + fl) = ph;
  }
}

template<int LAST>
__global__ __launch_bounds__(512, 4)
void k_fused(const ushortT* __restrict__ agg,
             const ushortT* __restrict__ WoT, const float* __restrict__ bo,
             const ushortT* __restrict__ WnT, ushortT* __restrict__ outH,
             const float* __restrict__ W1, const float* __restrict__ b1,
             const float* __restrict__ W2, const float* __restrict__ b2,
             float* __restrict__ u, int N){
  __shared__ ushortT vh[LAST ? 1 : 16 * TSTR];
  __shared__ float   vf[LAST ? 16 * VSTR : 1];
  int tid = threadIdx.x;
  int wave = tid >> 6, lane = tid & 63;
  int m = lane & 15, quad = lane >> 4;
  int rowBase = blockIdx.x << 4;
  int row = rowBase + m; if (row >= N) row = N - 1;
  int ncol = wave * 16 + m;

  bf16x8 b2f[4];
  if (!LAST){
    const ushortT* bp = WnT + ((size_t)ncol << 7) + quad*8;
    #pragma unroll
    for (int kk = 0; kk < 4; ++kk) b2f[kk] = *(const bf16x8*)(bp + kk*32);
  }
  {
    bf16x8 av[4];
    #pragma unroll
    for (int kk = 0; kk < 4; ++kk)
      av[kk] = *(const bf16x8*)(agg + ((size_t)row << 7) + kk*32 + quad*8);
    const ushortT* bp = WoT + ((size_t)ncol << 7) + quad*8;
    bf16x8 bb[4];
    #pragma unroll
    for (int kk = 0; kk < 4; ++kk) bb[kk] = *(const bf16x8*)(bp + kk*32);
    f32x4 d = mfma4r(av, bb);
    float bbias = bo[ncol];
    #pragma unroll
    for (int r = 0; r < 4; ++r){
      float sv = ssp(d[r] + bbias);
      if (LAST) vf[(quad*4 + r) * VSTR + ncol] = sv;
      else      vh[(quad*4 + r) * TSTR + ncol] = f2bf(sv);
    }
  }
  __syncthreads();

  if (!LAST){
    bf16x8 a2[4];
    #pragma unroll
    for (int kk = 0; kk < 4; ++kk)
      a2[kk] = *(const bf16x8*)(&vh[m * TSTR + kk*32 + quad*8]);
    f32x4 d = mfma4r(a2, b2f);
    #pragma unroll
    for (int r = 0; r < 4; ++r){
      int orow = rowBase + quad*4 + r;
      if (orow < N) outH[((size_t)orow << 7) + ncol] = f2bf(d[r]);
    }
  } else {
    #pragma unroll 1
    for (int i = 0; i < 2; ++i){
      int node = rowBase + wave*2 + i;
      if (node >= N) continue;
      const float* vrow = &vf[(wave*2 + i) * VSTR];
      float tt0 = b1[lane], tt1 = 0.f;
      #pragma unroll 8
      for (int k = 0; k < HDIM; k += 2){
        tt0 = fmaf(vrow[k],     W1[k * 64 + lane],       tt0);
        tt1 = fmaf(vrow[k + 1], W1[(k + 1) * 64 + lane], tt1);
      }
      float partial = ssp(tt0 + tt1) * W2[lane];
      #pragma unroll
      for (int off = 32; off > 0; off >>= 1)
        partial += __shfl_down(partial, off, 64);
      if (lane == 0) u[node] = partial + b2[0];
    }
  }
}

__global__ void k_gsum(const float* __restrict__ u, const int* __restrict__ groupOff,
                       float* __restrict__ out, int G){
  int g = blockIdx.x * 4 + (threadIdx.x >> 6);
  if (g >= G) return;
  int lane = threadIdx.x & 63;
  int s = groupOff[g], e = groupOff[g + 1];
  float acc = 0.f;
  for (int j = s + lane; j < e; j += 64) acc += u[j];
  #pragma unroll
  for (int off = 32; off > 0; off >>= 1)
    acc += __shfl_down(acc, off, 64);
  if (lane == 0) out[g] = acc;
}

extern "C" void kernel_launch(void* const* d_in, const int* in_sizes, int n_in,
                              void* d_out, int out_size, void* d_ws, size_t ws_size,
                              hipStream_t stream){
  const int N = in_sizes[0];
  const int E = in_sizes[3] / 2;
  const int G = out_size;

  char* ws = (char*)d_ws;
  size_t off = 0;
  auto alloc = [&](size_t bytes) -> char* {
    char* p = ws + off;
    off = (off + bytes + 255) & ~(size_t)255;
    return p;
  };

  MegaP p;
  p.z     = (const int*)d_in[0];
  p.pos   = (const float*)d_in[1];
  p.batch = (const int*)d_in[2];
  p.erow  = (const int*)d_in[3];
  p.ecol  = (const int*)d_in[3] + E;
  p.emb   = (const float*)d_in[4];
  p.dW    = (const float*)d_in[5];
  p.db    = (const float*)d_in[6];
  p.Wn    = (const float*)d_in[7];
  p.We    = (const float*)d_in[8];
  p.be    = (const float*)d_in[9];
  p.Wo    = (const float*)d_in[10];
  p.bo    = (const float*)d_in[11];
  p.W1    = (const float*)d_in[12];
  p.b1    = (const float*)d_in[13];
  p.W2    = (const float*)d_in[14];
  p.b2    = (const float*)d_in[15];

  p.counts   = (int*)         alloc((size_t)N * 4);
  p.offsets  = (int*)         alloc((size_t)(N + 1) * 4);
  p.cursor   = (int*)         alloc((size_t)N * 4);
  p.partials = (int*)         alloc((size_t)COOPG * 4);
  p.csr      = (unsigned int*)alloc((size_t)E * 4);
  p.h0       = (ushortT*)     alloc((size_t)N * HDIM * 2);
  p.h1       = (ushortT*)     alloc((size_t)N * HDIM * 2);
  p.vhi      = (ushortT*)     alloc((size_t)N * HDIM * 2);
  p.agg      = (ushortT*)     alloc((size_t)N * HDIM * 2);
  p.WnT      = (ushortT*)     alloc((size_t)NLAYER * HDIM * HDIM * 2);
  p.WoT      = (ushortT*)     alloc((size_t)NLAYER * HDIM * HDIM * 2);
  p.a        = (float*)       alloc((size_t)NLAYER * HDIM * 4);
  p.c        = (float*)       alloc((size_t)NLAYER * HDIM * 4);
  p.u        = (float*)       alloc((size_t)N * 4);
  p.groupOff = (int*)         alloc((size_t)(G + 1) * 4);
  p.out      = (float*)d_out;
  p.N = N; p.E = E; p.G = G;

  void* args[] = { &p };
  hipError_t err = hipLaunchCooperativeKernel((const void*)k_mega,
                                              dim3(COOPG), dim3(512), args, 0, stream);
  if (err != hipSuccess){
    // fallback: known-good multi-kernel path (deterministic: same error every call)
    int nscanb = (N + 255) / 256;
    int B0 = (N + 255) / 256;
    int B1 = (N * HDIM + 255) / 256;
    int B2 = (NLAYER * HDIM * HDIM + 255) / 256;
    int B4 = (NLAYER * HDIM + 255) / 256;
    int B5 = (N + 255) / 256;
    k_setup<<<B0 + B1 + 2*B2 + B4 + B5, 256, 0, stream>>>(
        p.z, p.emb, p.vhi, p.Wn, p.WnT, p.Wo, p.WoT,
        p.dW, p.db, p.We, p.be, p.a, p.c, p.batch, p.groupOff, p.counts,
        N, G, B0, B1, B2, B4, B5);
    k_count<<<(E + 255) / 256, 256, 0, stream>>>(p.erow, p.counts, E);
    k_scan1<<<nscanb, 256, 0, stream>>>(p.counts, p.partials, N);
    k_scan3<<<nscanb, 256, 0, stream>>>(p.counts, p.partials, p.offsets, p.cursor, N, nscanb);
    k_fill<<<(E + 255) / 256, 256, 0, stream>>>(p.erow, p.ecol, p.pos, p.cursor, p.csr, E);

    int ntiles = (N + 15) >> 4;
    int nwj = (ntiles + 1) / 2;
    int pairGrid = (nwj + 1) / 2;
    int nodeGrid = (N + 3) / 4;
    k_gemm0<<<pairGrid, 128, 0, stream>>>(p.vhi, p.WnT, p.h0, N);
    for (int l = 0; l < NLAYER; ++l){
      size_t wo = (size_t)l * HDIM * HDIM;
      const ushortT* hin  = (l & 1) ? p.h1 : p.h0;
      ushortT*       hout = (l & 1) ? p.h0 : p.h1;
      k_agg2<<<nodeGrid, 256, 0, stream>>>(hin, p.offsets, p.csr,
                                           p.a + l * HDIM, p.c + l * HDIM, p.agg, N);
      if (l < NLAYER - 1){
        size_t wn = (size_t)(l + 1) * HDIM * HDIM;
        k_fused<0><<<ntiles, 512, 0, stream>>>(p.agg, p.WoT + wo,
            p.bo + (size_t)l * HDIM, p.WnT + wn, hout,
            nullptr, nullptr, nullptr, nullptr, nullptr, N);
      } else {
        k_fused<1><<<ntiles, 512, 0, stream>>>(p.agg, p.WoT + wo,
            p.bo + (size_t)l * HDIM, nullptr, nullptr,
            p.W1, p.b1, p.W2, p.b2, p.u, N);
      }
    }
    k_gsum<<<(G + 3) / 4, 256, 0, stream>>>(p.u, p.groupOff, (float*)d_out, G);
  }
}

// Round 17
// 829.995 us; speedup vs baseline: 2.1492x; 2.1492x over previous
//
#include <hip/hip_runtime.h>
#include <math.h>

#define HDIM 128
#define NGAUSS 50
#define NLAYER 6
#define TSTR 136   // LDS bf16 tile row stride (shorts)
#define VSTR 132   // LDS f32 tile row stride (floats)
#define DINV (1.0f/512.0f)
#define NXCD 8

typedef unsigned short ushortT;
typedef __attribute__((ext_vector_type(8))) short bf16x8;
typedef __attribute__((ext_vector_type(4))) float f32x4;

static __device__ __forceinline__ float bf2f(unsigned short u){
  union { unsigned int i; float f; } x; x.i = ((unsigned int)u) << 16; return x.f;
}
static __device__ __forceinline__ unsigned short f2bf(float f){
  union { float f; unsigned int i; } x; x.f = f;
  unsigned int i = x.i;
  unsigned int r = (i + 0x7FFFu + ((i >> 16) & 1u)) >> 16;
  return (unsigned short)r;
}
static __device__ __forceinline__ float ssp(float x){
  return fmaxf(x, 0.0f) + __logf(1.0f + __expf(-fabsf(x))) - 0.69314718055994530942f;
}
static __device__ __forceinline__ f32x4 mfma4r(const bf16x8* a, const bf16x8* b){
  f32x4 d = {0.f, 0.f, 0.f, 0.f};
  d = __builtin_amdgcn_mfma_f32_16x16x32_bf16(a[0], b[0], d, 0, 0, 0);
  d = __builtin_amdgcn_mfma_f32_16x16x32_bf16(a[1], b[1], d, 0, 0, 0);
  d = __builtin_amdgcn_mfma_f32_16x16x32_bf16(a[2], b[2], d, 0, 0, 0);
  d = __builtin_amdgcn_mfma_f32_16x16x32_bf16(a[3], b[3], d, 0, 0, 0);
  return d;
}

// ---------------- CSR build ----------------
__global__ void k_count(const int* __restrict__ row, int* __restrict__ counts, int E){
  int e = blockIdx.x * 256 + threadIdx.x;
  if (e < E) atomicAdd(&counts[row[e]], 1);
}

__global__ void k_scan1(const int* __restrict__ counts, int* __restrict__ blockSums, int N){
  __shared__ int red[256];
  int tid = threadIdx.x;
  int i = blockIdx.x * 256 + tid;
  red[tid] = (i < N) ? counts[i] : 0;
  __syncthreads();
  #pragma unroll
  for (int off = 128; off > 0; off >>= 1){
    if (tid < off) red[tid] += red[tid + off];
    __syncthreads();
  }
  if (tid == 0) blockSums[blockIdx.x] = red[0];
}

__global__ void k_scan3(const int* __restrict__ counts, const int* __restrict__ blockSums,
                        int* __restrict__ offsets, int* __restrict__ cursor, int N, int nb){
  __shared__ int bs[256];
  __shared__ int s[256];
  int tid = threadIdx.x;
  bs[tid] = (tid < nb) ? blockSums[tid] : 0;
  __syncthreads();
  #pragma unroll
  for (int off = 1; off < 256; off <<= 1){
    int t = (tid >= off) ? bs[tid - off] : 0;
    __syncthreads();
    bs[tid] += t;
    __syncthreads();
  }
  int myOff = (blockIdx.x == 0) ? 0 : bs[blockIdx.x - 1];
  int i = blockIdx.x * 256 + tid;
  int v = (i < N) ? counts[i] : 0;
  s[tid] = v;
  __syncthreads();
  #pragma unroll
  for (int off = 1; off < 256; off <<= 1){
    int t = (tid >= off) ? s[tid - off] : 0;
    __syncthreads();
    s[tid] += t;
    __syncthreads();
  }
  int excl = myOff + s[tid] - v;
  if (i < N){ offsets[i] = excl; cursor[i] = excl; }
  if (i == N - 1) offsets[N] = excl + v;
}

// csr record: col<<16 | round(dist*512)
__global__ void k_fill(const int* __restrict__ row, const int* __restrict__ col,
                       const float* __restrict__ pos, int* __restrict__ cursor,
                       unsigned int* __restrict__ csr, int E){
  int e = blockIdx.x * 256 + threadIdx.x;
  if (e >= E) return;
  int r = row[e], c = col[e];
  float dx = pos[r*3+0] - pos[c*3+0];
  float dy = pos[r*3+1] - pos[c*3+1];
  float dz = pos[r*3+2] - pos[c*3+2];
  float d = sqrtf(dx*dx + dy*dy + dz*dz);
  int du = (int)(d * 512.0f + 0.5f);
  if (du > 65535) du = 65535;
  int slot = atomicAdd(&cursor[r], 1);
  csr[slot] = ((unsigned int)c << 16) | (unsigned int)du;
}

// ---------------- merged elementwise setup ----------------
__global__ void k_setup(const int* __restrict__ z, const float* __restrict__ emb,
                        ushortT* __restrict__ vhi,
                        const float* __restrict__ Wn, ushortT* __restrict__ WnT,
                        const float* __restrict__ Wo, ushortT* __restrict__ WoT,
                        const float* __restrict__ dW, const float* __restrict__ db,
                        const float* __restrict__ We, const float* __restrict__ be,
                        float* __restrict__ a, float* __restrict__ c,
                        const int* __restrict__ batch, int* __restrict__ groupOff,
                        int* __restrict__ counts,
                        int N, int G, int B0, int B1, int B2, int B4, int B5){
  int b = blockIdx.x;
  int tid = threadIdx.x;
  if (b < B0){
    int i = b * 256 + tid;
    if (i < N) counts[i] = 0;
    return;
  }
  b -= B0;
  if (b < B1){
    int idx = b * 256 + tid;
    if (idx < N * HDIM){
      int n = idx >> 7, f = idx & 127;
      vhi[idx] = f2bf(emb[z[n] * HDIM + f]);
    }
    return;
  }
  b -= B1;
  if (b < B2){
    int idx = b * 256 + tid;
    if (idx < NLAYER * HDIM * HDIM){
      int mat = idx >> 14, rem = idx & 16383;
      int n = rem >> 7, k = rem & 127;
      WnT[idx] = f2bf(Wn[(mat << 14) + k * HDIM + n]);
    }
    return;
  }
  b -= B2;
  if (b < B2){
    int idx = b * 256 + tid;
    if (idx < NLAYER * HDIM * HDIM){
      int mat = idx >> 14, rem = idx & 16383;
      int n = rem >> 7, k = rem & 127;
      WoT[idx] = f2bf(Wo[(mat << 14) + k * HDIM + n]);
    }
    return;
  }
  b -= B2;
  if (b < B4){
    int idx = b * 256 + tid;
    if (idx < NLAYER * HDIM){
      int l = idx >> 7, f = idx & 127;
      float av = 0.f, cv = 0.f;
      for (int g = 0; g < NGAUSS; ++g){
        float we = We[(l * NGAUSS + g) * HDIM + f];
        av += dW[g] * we;
        cv += db[g] * we;
      }
      a[idx] = av;
      c[idx] = cv + be[idx];
    }
    return;
  }
  b -= B4;
  if (b < B5){
    int i = b * 256 + tid;
    if (i >= N) return;
    int bb = batch[i];
    if (i == 0){
      for (int g = 0; g <= bb; ++g) groupOff[g] = 0;
    } else {
      int pb = batch[i - 1];
      for (int g = pb + 1; g <= bb; ++g) groupOff[g] = i;
    }
    if (i == N - 1){
      for (int g = bb + 1; g <= G; ++g) groupOff[g] = N;
    }
  }
}

// ---------------- initial GEMM: h0 = v0 @ Wn[0]; 2 row-tiles per wave ----------
__global__ __launch_bounds__(128, 2)
void k_gemm0(const ushortT* __restrict__ X, const ushortT* __restrict__ WT,
             ushortT* __restrict__ outHi, int N){
  int tid = threadIdx.x;
  int wave = tid >> 6, lane = tid & 63;
  int m = lane & 15, quad = lane >> 4;
  int ntiles = (N + 15) >> 4;
  int t0 = (blockIdx.x * 2 + wave) * 2;
  if (t0 >= ntiles) return;

  bf16x8 av[2][4];
  #pragma unroll
  for (int rt = 0; rt < 2; ++rt){
    int row = (t0 + rt) * 16 + m; if (row >= N) row = N - 1;
    #pragma unroll
    for (int kk = 0; kk < 4; ++kk)
      av[rt][kk] = *(const bf16x8*)(X + ((size_t)row << 7) + kk*32 + quad*8);
  }
  #pragma unroll
  for (int ct = 0; ct < 8; ++ct){
    int ncol = ct * 16 + m;
    const ushortT* bp = WT + ((size_t)ncol << 7) + quad*8;
    bf16x8 bb[4];
    #pragma unroll
    for (int kk = 0; kk < 4; ++kk) bb[kk] = *(const bf16x8*)(bp + kk*32);
    #pragma unroll
    for (int rt = 0; rt < 2; ++rt){
      f32x4 d = mfma4r(av[rt], bb);
      #pragma unroll
      for (int r = 0; r < 4; ++r){
        int orow = (t0 + rt) * 16 + quad*4 + r;
        if (orow < N) outHi[((size_t)orow << 7) + ncol] = f2bf(d[r]);
      }
    }
  }
}

// ---------------- edge aggregation, XCD-swizzled node ownership ----------------
// blockIdx % 8 -> XCD s (dispatch heuristic); XCD s owns nodes
// [s*segNodes, (s+1)*segNodes) so agg[] rows land in XCD-s L2 for k_fused.
__global__ __launch_bounds__(256, 8)
void k_agg2(const ushortT* __restrict__ h, const int* __restrict__ offsets,
            const unsigned int* __restrict__ cd, const float* __restrict__ a,
            const float* __restrict__ c, ushortT* __restrict__ aggHi,
            int N, int segNodes){
  int xcd = blockIdx.x & (NXCD - 1);
  int idx = blockIdx.x >> 3;
  int node = xcd * segNodes + idx * 4 + (threadIdx.x >> 6);
  if (node >= N || node >= (xcd + 1) * segNodes) return;
  int lane = threadIdx.x & 63;
  int half = lane >> 5;
  int fl = (lane & 31) * 4;
  float4 av = *(const float4*)(a + fl);
  float4 cv = *(const float4*)(c + fl);
  int s = offsets[node], e = offsets[node + 1];
  float acc0 = 0.f, acc1 = 0.f, acc2 = 0.f, acc3 = 0.f;
  int j = s;
  for (; j + 8 <= e; j += 8){
    unsigned int q[4]; uint2 p[4];
    #pragma unroll
    for (int i = 0; i < 4; ++i) q[i] = cd[j + 2*i + half];
    #pragma unroll
    for (int i = 0; i < 4; ++i)
      p[i] = *(const uint2*)(h + ((size_t)(q[i] >> 16) << 7) + fl);
    #pragma unroll
    for (int i = 0; i < 4; ++i){
      float dd = (float)(q[i] & 0xFFFFu) * DINV;
      acc0 = fmaf(bf2f((ushortT)p[i].x),         fmaf(dd, av.x, cv.x), acc0);
      acc1 = fmaf(bf2f((ushortT)(p[i].x >> 16)), fmaf(dd, av.y, cv.y), acc1);
      acc2 = fmaf(bf2f((ushortT)p[i].y),         fmaf(dd, av.z, cv.z), acc2);
      acc3 = fmaf(bf2f((ushortT)(p[i].y >> 16)), fmaf(dd, av.w, cv.w), acc3);
    }
  }
  for (; j < e; j += 2){
    int myj = j + half;
    if (myj < e){
      unsigned int q = cd[myj];
      uint2 p = *(const uint2*)(h + ((size_t)(q >> 16) << 7) + fl);
      float dd = (float)(q & 0xFFFFu) * DINV;
      acc0 = fmaf(bf2f((ushortT)p.x),         fmaf(dd, av.x, cv.x), acc0);
      acc1 = fmaf(bf2f((ushortT)(p.x >> 16)), fmaf(dd, av.y, cv.y), acc1);
      acc2 = fmaf(bf2f((ushortT)p.y),         fmaf(dd, av.z, cv.z), acc2);
      acc3 = fmaf(bf2f((ushortT)(p.y >> 16)), fmaf(dd, av.w, cv.w), acc3);
    }
  }
  acc0 += __shfl_down(acc0, 32, 64);
  acc1 += __shfl_down(acc1, 32, 64);
  acc2 += __shfl_down(acc2, 32, 64);
  acc3 += __shfl_down(acc3, 32, 64);
  if (half == 0){
    uint2 ph;
    ph.x = (unsigned int)f2bf(acc0) | ((unsigned int)f2bf(acc1) << 16);
    ph.y = (unsigned int)f2bf(acc2) | ((unsigned int)f2bf(acc3) << 16);
    *(uint2*)(aggHi + ((size_t)node << 7) + fl) = ph;
  }
}

// ---------------- fused GEMM pair, XCD-swizzled tile ownership ----------------
// Same segment map as k_agg2: tile t belongs to XCD t/segTiles, so the agg rows
// this block reads were written into this XCD's L2.
template<int LAST>
__global__ __launch_bounds__(512, 4)
void k_fused(const ushortT* __restrict__ agg,
             const ushortT* __restrict__ WoT, const float* __restrict__ bo,
             const ushortT* __restrict__ WnT, ushortT* __restrict__ outH,
             const float* __restrict__ W1, const float* __restrict__ b1,
             const float* __restrict__ W2, const float* __restrict__ b2,
             float* __restrict__ u, int N, int segTiles){
  __shared__ ushortT vh[LAST ? 1 : 16 * TSTR];
  __shared__ float   vf[LAST ? 16 * VSTR : 1];
  int ntiles = (N + 15) >> 4;
  int xcd = blockIdx.x & (NXCD - 1);
  int idx = blockIdx.x >> 3;
  int tile = xcd * segTiles + idx;
  if (idx >= segTiles || tile >= ntiles) return;
  int tid = threadIdx.x;
  int wave = tid >> 6, lane = tid & 63;
  int m = lane & 15, quad = lane >> 4;
  int rowBase = tile << 4;
  int row = rowBase + m; if (row >= N) row = N - 1;
  int ncol = wave * 16 + m;

  bf16x8 b2f[4];
  if (!LAST){
    const ushortT* bp = WnT + ((size_t)ncol << 7) + quad*8;
    #pragma unroll
    for (int kk = 0; kk < 4; ++kk) b2f[kk] = *(const bf16x8*)(bp + kk*32);
  }
  {
    bf16x8 av[4];
    #pragma unroll
    for (int kk = 0; kk < 4; ++kk)
      av[kk] = *(const bf16x8*)(agg + ((size_t)row << 7) + kk*32 + quad*8);
    const ushortT* bp = WoT + ((size_t)ncol << 7) + quad*8;
    bf16x8 bb[4];
    #pragma unroll
    for (int kk = 0; kk < 4; ++kk) bb[kk] = *(const bf16x8*)(bp + kk*32);
    f32x4 d = mfma4r(av, bb);
    float bbias = bo[ncol];
    #pragma unroll
    for (int r = 0; r < 4; ++r){
      float sv = ssp(d[r] + bbias);
      if (LAST) vf[(quad*4 + r) * VSTR + ncol] = sv;
      else      vh[(quad*4 + r) * TSTR + ncol] = f2bf(sv);
    }
  }
  __syncthreads();

  if (!LAST){
    bf16x8 a2[4];
    #pragma unroll
    for (int kk = 0; kk < 4; ++kk)
      a2[kk] = *(const bf16x8*)(&vh[m * TSTR + kk*32 + quad*8]);
    f32x4 d = mfma4r(a2, b2f);
    #pragma unroll
    for (int r = 0; r < 4; ++r){
      int orow = rowBase + quad*4 + r;
      if (orow < N) outH[((size_t)orow << 7) + ncol] = f2bf(d[r]);
    }
  } else {
    #pragma unroll 1
    for (int i = 0; i < 2; ++i){
      int node = rowBase + wave*2 + i;
      if (node >= N) continue;
      const float* vrow = &vf[(wave*2 + i) * VSTR];
      float tt0 = b1[lane], tt1 = 0.f;
      #pragma unroll 8
      for (int k = 0; k < HDIM; k += 2){
        tt0 = fmaf(vrow[k],     W1[k * 64 + lane],       tt0);
        tt1 = fmaf(vrow[k + 1], W1[(k + 1) * 64 + lane], tt1);
      }
      float partial = ssp(tt0 + tt1) * W2[lane];
      #pragma unroll
      for (int off = 32; off > 0; off >>= 1)
        partial += __shfl_down(partial, off, 64);
      if (lane == 0) u[node] = partial + b2[0];
    }
  }
}

// ---------------- group segment sum over sorted batch ----------------
__global__ void k_gsum(const float* __restrict__ u, const int* __restrict__ groupOff,
                       float* __restrict__ out, int G){
  int g = blockIdx.x * 4 + (threadIdx.x >> 6);
  if (g >= G) return;
  int lane = threadIdx.x & 63;
  int s = groupOff[g], e = groupOff[g + 1];
  float acc = 0.f;
  for (int j = s + lane; j < e; j += 64) acc += u[j];
  #pragma unroll
  for (int off = 32; off > 0; off >>= 1)
    acc += __shfl_down(acc, off, 64);
  if (lane == 0) out[g] = acc;
}

extern "C" void kernel_launch(void* const* d_in, const int* in_sizes, int n_in,
                              void* d_out, int out_size, void* d_ws, size_t ws_size,
                              hipStream_t stream){
  const int N = in_sizes[0];
  const int E = in_sizes[3] / 2;
  const int G = out_size;

  const int*   z     = (const int*)d_in[0];
  const float* pos   = (const float*)d_in[1];
  const int*   batch = (const int*)d_in[2];
  const int*   eidx  = (const int*)d_in[3];
  const int*   erow  = eidx;
  const int*   ecol  = eidx + E;
  const float* emb   = (const float*)d_in[4];
  const float* dW    = (const float*)d_in[5];
  const float* db    = (const float*)d_in[6];
  const float* Wn    = (const float*)d_in[7];
  const float* We    = (const float*)d_in[8];
  const float* be    = (const float*)d_in[9];
  const float* Wo    = (const float*)d_in[10];
  const float* bo    = (const float*)d_in[11];
  const float* W1    = (const float*)d_in[12];
  const float* b1    = (const float*)d_in[13];
  const float* W2    = (const float*)d_in[14];
  const float* b2    = (const float*)d_in[15];

  char* ws = (char*)d_ws;
  size_t off = 0;
  auto alloc = [&](size_t bytes) -> char* {
    char* p = ws + off;
    off = (off + bytes + 255) & ~(size_t)255;
    return p;
  };
  int nscanb = (N + 255) / 256;
  int*          counts   = (int*)         alloc((size_t)N * 4);
  int*          offsets  = (int*)         alloc((size_t)(N + 1) * 4);
  int*          cursor   = (int*)         alloc((size_t)N * 4);
  int*          blockSums= (int*)         alloc((size_t)nscanb * 4);
  unsigned int* csr      = (unsigned int*)alloc((size_t)E * 4);
  ushortT*      h0       = (ushortT*)     alloc((size_t)N * HDIM * 2);
  ushortT*      h1       = (ushortT*)     alloc((size_t)N * HDIM * 2);
  ushortT*      vhi      = (ushortT*)     alloc((size_t)N * HDIM * 2);
  ushortT*      agghi    = (ushortT*)     alloc((size_t)N * HDIM * 2);
  ushortT*      WnT      = (ushortT*)     alloc((size_t)NLAYER * HDIM * HDIM * 2);
  ushortT*      WoT      = (ushortT*)     alloc((size_t)NLAYER * HDIM * HDIM * 2);
  float*        a        = (float*)       alloc((size_t)NLAYER * HDIM * 4);
  float*        c        = (float*)       alloc((size_t)NLAYER * HDIM * 4);
  float*        u        = (float*)       alloc((size_t)N * 4);
  int*          groupOff = (int*)         alloc((size_t)(G + 1) * 4);

  int B0 = (N + 255) / 256;
  int B1 = (N * HDIM + 255) / 256;
  int B2 = (NLAYER * HDIM * HDIM + 255) / 256;
  int B4 = (NLAYER * HDIM + 255) / 256;
  int B5 = (N + 255) / 256;
  k_setup<<<B0 + B1 + 2*B2 + B4 + B5, 256, 0, stream>>>(
      z, emb, vhi, Wn, WnT, Wo, WoT,
      dW, db, We, be, a, c, batch, groupOff, counts, N, G, B0, B1, B2, B4, B5);

  k_count<<<(E + 255) / 256, 256, 0, stream>>>(erow, counts, E);
  k_scan1<<<nscanb, 256, 0, stream>>>(counts, blockSums, N);
  k_scan3<<<nscanb, 256, 0, stream>>>(counts, blockSums, offsets, cursor, N, nscanb);
  k_fill<<<(E + 255) / 256, 256, 0, stream>>>(erow, ecol, pos, cursor, csr, E);

  int ntiles = (N + 15) >> 4;
  int segTiles = (ntiles + NXCD - 1) / NXCD;       // tiles per XCD segment
  int segNodes = segTiles * 16;                    // nodes per XCD segment (mult of 4)
  int aggGrid  = NXCD * ((segNodes + 3) / 4);
  int fusedGrid = NXCD * segTiles;
  int nwj = (ntiles + 1) / 2;
  int pairGrid = (nwj + 1) / 2;
  k_gemm0<<<pairGrid, 128, 0, stream>>>(vhi, WnT, h0, N);

  for (int l = 0; l < NLAYER; ++l){
    size_t wo = (size_t)l * HDIM * HDIM;
    const ushortT* hin  = (l & 1) ? h1 : h0;
    ushortT*       hout = (l & 1) ? h0 : h1;
    k_agg2<<<aggGrid, 256, 0, stream>>>(hin, offsets, csr,
                                        a + l * HDIM, c + l * HDIM, agghi, N, segNodes);
    if (l < NLAYER - 1){
      size_t wn = (size_t)(l + 1) * HDIM * HDIM;
      k_fused<0><<<fusedGrid, 512, 0, stream>>>(agghi, WoT + wo,
          bo + (size_t)l * HDIM, WnT + wn, hout,
          nullptr, nullptr, nullptr, nullptr, nullptr, N, segTiles);
    } else {
      k_fused<1><<<fusedGrid, 512, 0, stream>>>(agghi, WoT + wo,
          bo + (size_t)l * HDIM, nullptr, nullptr,
          W1, b1, W2, b2, u, N, segTiles);
    }
  }
  k_gsum<<<(G + 3) / 4, 256, 0, stream>>>(u, groupOff, (float*)d_out, G);
}

// Round 18
// 807.974 us; speedup vs baseline: 2.2078x; 1.0273x over previous
//
#include <hip/hip_runtime.h>
#include <math.h>

#define HDIM 128
#define NGAUSS 50
#define NLAYER 6
#define DINV (1.0f/512.0f)
#define NXCD 8

typedef unsigned short ushortT;
typedef __attribute__((ext_vector_type(8))) short bf16x8;
typedef __attribute__((ext_vector_type(4))) float f32x4;

static __device__ __forceinline__ float bf2f(unsigned short u){
  union { unsigned int i; float f; } x; x.i = ((unsigned int)u) << 16; return x.f;
}
static __device__ __forceinline__ unsigned short f2bf(float f){
  union { float f; unsigned int i; } x; x.f = f;
  unsigned int i = x.i;
  unsigned int r = (i + 0x7FFFu + ((i >> 16) & 1u)) >> 16;
  return (unsigned short)r;
}
static __device__ __forceinline__ float ssp(float x){
  return fmaxf(x, 0.0f) + __logf(1.0f + __expf(-fabsf(x))) - 0.69314718055994530942f;
}
static __device__ __forceinline__ f32x4 mfma4r(const bf16x8* a, const bf16x8* b){
  f32x4 d = {0.f, 0.f, 0.f, 0.f};
  d = __builtin_amdgcn_mfma_f32_16x16x32_bf16(a[0], b[0], d, 0, 0, 0);
  d = __builtin_amdgcn_mfma_f32_16x16x32_bf16(a[1], b[1], d, 0, 0, 0);
  d = __builtin_amdgcn_mfma_f32_16x16x32_bf16(a[2], b[2], d, 0, 0, 0);
  d = __builtin_amdgcn_mfma_f32_16x16x32_bf16(a[3], b[3], d, 0, 0, 0);
  return d;
}

// ---------------- scans ----------------
__global__ void k_scan1(const int* __restrict__ counts, int* __restrict__ blockSums, int N){
  __shared__ int red[256];
  int tid = threadIdx.x;
  int i = blockIdx.x * 256 + tid;
  red[tid] = (i < N) ? counts[i] : 0;
  __syncthreads();
  #pragma unroll
  for (int off = 128; off > 0; off >>= 1){
    if (tid < off) red[tid] += red[tid + off];
    __syncthreads();
  }
  if (tid == 0) blockSums[blockIdx.x] = red[0];
}

__global__ void k_scan3(const int* __restrict__ counts, const int* __restrict__ blockSums,
                        int* __restrict__ offsets, int* __restrict__ cursor, int N, int nb){
  __shared__ int bs[256];
  __shared__ int s[256];
  int tid = threadIdx.x;
  bs[tid] = (tid < nb) ? blockSums[tid] : 0;
  __syncthreads();
  #pragma unroll
  for (int off = 1; off < 256; off <<= 1){
    int t = (tid >= off) ? bs[tid - off] : 0;
    __syncthreads();
    bs[tid] += t;
    __syncthreads();
  }
  int myOff = (blockIdx.x == 0) ? 0 : bs[blockIdx.x - 1];
  int i = blockIdx.x * 256 + tid;
  int v = (i < N) ? counts[i] : 0;
  s[tid] = v;
  __syncthreads();
  #pragma unroll
  for (int off = 1; off < 256; off <<= 1){
    int t = (tid >= off) ? s[tid - off] : 0;
    __syncthreads();
    s[tid] += t;
    __syncthreads();
  }
  int excl = myOff + s[tid] - v;
  if (i < N){ offsets[i] = excl; cursor[i] = excl; }
  if (i == N - 1) offsets[N] = excl + v;
}

// csr record: col<<16 | round(dist*512)
__global__ void k_fill(const int* __restrict__ row, const int* __restrict__ col,
                       const float* __restrict__ pos, int* __restrict__ cursor,
                       unsigned int* __restrict__ csr, int E){
  int e = blockIdx.x * 256 + threadIdx.x;
  if (e >= E) return;
  int r = row[e], c = col[e];
  float dx = pos[r*3+0] - pos[c*3+0];
  float dy = pos[r*3+1] - pos[c*3+1];
  float dz = pos[r*3+2] - pos[c*3+2];
  float d = sqrtf(dx*dx + dy*dy + dz*dz);
  int du = (int)(d * 512.0f + 0.5f);
  if (du > 65535) du = 65535;
  int slot = atomicAdd(&cursor[r], 1);
  csr[slot] = ((unsigned int)c << 16) | (unsigned int)du;
}

// ---------------- merged setup (+ degree count; counts pre-zeroed by memset) ---
__global__ void k_setup(const int* __restrict__ z, const float* __restrict__ emb,
                        ushortT* __restrict__ vhi,
                        const float* __restrict__ Wn, ushortT* __restrict__ WnT,
                        const float* __restrict__ Wo, ushortT* __restrict__ WoT,
                        const float* __restrict__ dW, const float* __restrict__ db,
                        const float* __restrict__ We, const float* __restrict__ be,
                        float* __restrict__ a, float* __restrict__ c,
                        const int* __restrict__ batch, int* __restrict__ groupOff,
                        const int* __restrict__ erow, int* __restrict__ counts,
                        int N, int E, int G, int B1, int B2, int B4, int B5, int B6){
  int b = blockIdx.x;
  int tid = threadIdx.x;
  if (b < B1){
    int idx = b * 256 + tid;
    if (idx < N * HDIM){
      int n = idx >> 7, f = idx & 127;
      vhi[idx] = f2bf(emb[z[n] * HDIM + f]);
    }
    return;
  }
  b -= B1;
  if (b < B2){
    int idx = b * 256 + tid;
    if (idx < NLAYER * HDIM * HDIM){
      int mat = idx >> 14, rem = idx & 16383;
      int n = rem >> 7, k = rem & 127;
      WnT[idx] = f2bf(Wn[(mat << 14) + k * HDIM + n]);
    }
    return;
  }
  b -= B2;
  if (b < B2){
    int idx = b * 256 + tid;
    if (idx < NLAYER * HDIM * HDIM){
      int mat = idx >> 14, rem = idx & 16383;
      int n = rem >> 7, k = rem & 127;
      WoT[idx] = f2bf(Wo[(mat << 14) + k * HDIM + n]);
    }
    return;
  }
  b -= B2;
  if (b < B4){
    int idx = b * 256 + tid;
    if (idx < NLAYER * HDIM){
      int l = idx >> 7, f = idx & 127;
      float av = 0.f, cv = 0.f;
      for (int g = 0; g < NGAUSS; ++g){
        float we = We[(l * NGAUSS + g) * HDIM + f];
        av += dW[g] * we;
        cv += db[g] * we;
      }
      a[idx] = av;
      c[idx] = cv + be[idx];
    }
    return;
  }
  b -= B4;
  if (b < B5){
    int i = b * 256 + tid;
    if (i >= N) return;
    int bb = batch[i];
    if (i == 0){
      for (int g = 0; g <= bb; ++g) groupOff[g] = 0;
    } else {
      int pb = batch[i - 1];
      for (int g = pb + 1; g <= bb; ++g) groupOff[g] = i;
    }
    if (i == N - 1){
      for (int g = bb + 1; g <= G; ++g) groupOff[g] = N;
    }
    return;
  }
  b -= B5;
  if (b < B6){
    int e = b * 256 + tid;
    if (e < E) atomicAdd(&counts[erow[e]], 1);
  }
}

// ---------------- initial GEMM: h0 = v0 @ Wn[0]; 2 row-tiles per wave ----------
__global__ __launch_bounds__(128, 2)
void k_gemm0(const ushortT* __restrict__ X, const ushortT* __restrict__ WT,
             ushortT* __restrict__ outHi, int N){
  int tid = threadIdx.x;
  int wave = tid >> 6, lane = tid & 63;
  int m = lane & 15, quad = lane >> 4;
  int ntiles = (N + 15) >> 4;
  int t0 = (blockIdx.x * 2 + wave) * 2;
  if (t0 >= ntiles) return;

  bf16x8 av[2][4];
  #pragma unroll
  for (int rt = 0; rt < 2; ++rt){
    int row = (t0 + rt) * 16 + m; if (row >= N) row = N - 1;
    #pragma unroll
    for (int kk = 0; kk < 4; ++kk)
      av[rt][kk] = *(const bf16x8*)(X + ((size_t)row << 7) + kk*32 + quad*8);
  }
  #pragma unroll
  for (int ct = 0; ct < 8; ++ct){
    int ncol = ct * 16 + m;
    const ushortT* bp = WT + ((size_t)ncol << 7) + quad*8;
    bf16x8 bb[4];
    #pragma unroll
    for (int kk = 0; kk < 4; ++kk) bb[kk] = *(const bf16x8*)(bp + kk*32);
    #pragma unroll
    for (int rt = 0; rt < 2; ++rt){
      f32x4 d = mfma4r(av[rt], bb);
      #pragma unroll
      for (int r = 0; r < 4; ++r){
        int orow = (t0 + rt) * 16 + quad*4 + r;
        if (orow < N) outHi[((size_t)orow << 7) + ncol] = f2bf(d[r]);
      }
    }
  }
}

// ---------------- edge aggregation, XCD-swizzled node ownership ----------------
__global__ __launch_bounds__(256, 8)
void k_agg2(const ushortT* __restrict__ h, const int* __restrict__ offsets,
            const unsigned int* __restrict__ cd, const float* __restrict__ a,
            const float* __restrict__ c, ushortT* __restrict__ aggHi,
            int N, int segNodes){
  int xcd = blockIdx.x & (NXCD - 1);
  int idx = blockIdx.x >> 3;
  int node = xcd * segNodes + idx * 4 + (threadIdx.x >> 6);
  if (node >= N || node >= (xcd + 1) * segNodes) return;
  int lane = threadIdx.x & 63;
  int half = lane >> 5;
  int fl = (lane & 31) * 4;
  float4 av = *(const float4*)(a + fl);
  float4 cv = *(const float4*)(c + fl);
  int s = offsets[node], e = offsets[node + 1];
  float acc0 = 0.f, acc1 = 0.f, acc2 = 0.f, acc3 = 0.f;
  int j = s;
  for (; j + 8 <= e; j += 8){
    unsigned int q[4]; uint2 p[4];
    #pragma unroll
    for (int i = 0; i < 4; ++i) q[i] = cd[j + 2*i + half];
    #pragma unroll
    for (int i = 0; i < 4; ++i)
      p[i] = *(const uint2*)(h + ((size_t)(q[i] >> 16) << 7) + fl);
    #pragma unroll
    for (int i = 0; i < 4; ++i){
      float dd = (float)(q[i] & 0xFFFFu) * DINV;
      acc0 = fmaf(bf2f((ushortT)p[i].x),         fmaf(dd, av.x, cv.x), acc0);
      acc1 = fmaf(bf2f((ushortT)(p[i].x >> 16)), fmaf(dd, av.y, cv.y), acc1);
      acc2 = fmaf(bf2f((ushortT)p[i].y),         fmaf(dd, av.z, cv.z), acc2);
      acc3 = fmaf(bf2f((ushortT)(p[i].y >> 16)), fmaf(dd, av.w, cv.w), acc3);
    }
  }
  for (; j < e; j += 2){
    int myj = j + half;
    if (myj < e){
      unsigned int q = cd[myj];
      uint2 p = *(const uint2*)(h + ((size_t)(q >> 16) << 7) + fl);
      float dd = (float)(q & 0xFFFFu) * DINV;
      acc0 = fmaf(bf2f((ushortT)p.x),         fmaf(dd, av.x, cv.x), acc0);
      acc1 = fmaf(bf2f((ushortT)(p.x >> 16)), fmaf(dd, av.y, cv.y), acc1);
      acc2 = fmaf(bf2f((ushortT)p.y),         fmaf(dd, av.z, cv.z), acc2);
      acc3 = fmaf(bf2f((ushortT)(p.y >> 16)), fmaf(dd, av.w, cv.w), acc3);
    }
  }
  acc0 += __shfl_down(acc0, 32, 64);
  acc1 += __shfl_down(acc1, 32, 64);
  acc2 += __shfl_down(acc2, 32, 64);
  acc3 += __shfl_down(acc3, 32, 64);
  if (half == 0){
    uint2 ph;
    ph.x = (unsigned int)f2bf(acc0) | ((unsigned int)f2bf(acc1) << 16);
    ph.y = (unsigned int)f2bf(acc2) | ((unsigned int)f2bf(acc3) << 16);
    *(uint2*)(aggHi + ((size_t)node << 7) + fl) = ph;
  }
}

// ---------------- barrier-free GEMM 1: v = ssp(agg @ Wo + bo) -> vb (bf16) ----
// gemm0 shape: 128 threads, 2 waves; wave = 2 row-tiles, serial over 8 cts,
// B loaded once per ct. XCD-swizzled tile segments match k_agg2's writer map.
__global__ __launch_bounds__(128, 2)
void k_g1(const ushortT* __restrict__ agg, const ushortT* __restrict__ WoT,
          const float* __restrict__ bo, ushortT* __restrict__ vb,
          int N, int segTiles){
  int tid = threadIdx.x;
  int wave = tid >> 6, lane = tid & 63;
  int m = lane & 15, quad = lane >> 4;
  int ntiles = (N + 15) >> 4;
  int xcd = blockIdx.x & (NXCD - 1);
  int idx = blockIdx.x >> 3;
  int wjIdx = idx * 2 + wave;              // wave-job within segment
  int segWJ = segTiles >> 1;
  if (wjIdx >= segWJ) return;
  int t0 = xcd * segTiles + wjIdx * 2;
  if (t0 >= ntiles) return;

  bf16x8 av[2][4];
  #pragma unroll
  for (int rt = 0; rt < 2; ++rt){
    int row = (t0 + rt) * 16 + m; if (row >= N) row = N - 1;
    #pragma unroll
    for (int kk = 0; kk < 4; ++kk)
      av[rt][kk] = *(const bf16x8*)(agg + ((size_t)row << 7) + kk*32 + quad*8);
  }
  #pragma unroll
  for (int ct = 0; ct < 8; ++ct){
    int ncol = ct * 16 + m;
    const ushortT* bp = WoT + ((size_t)ncol << 7) + quad*8;
    bf16x8 bb[4];
    #pragma unroll
    for (int kk = 0; kk < 4; ++kk) bb[kk] = *(const bf16x8*)(bp + kk*32);
    float bbias = bo[ncol];
    #pragma unroll
    for (int rt = 0; rt < 2; ++rt){
      f32x4 d = mfma4r(av[rt], bb);
      #pragma unroll
      for (int r = 0; r < 4; ++r){
        int orow = (t0 + rt) * 16 + quad*4 + r;
        if (orow < N) vb[((size_t)orow << 7) + ncol] = f2bf(ssp(d[r] + bbias));
      }
    }
  }
}

// ---------------- barrier-free GEMM 2: h' = vb @ Wn ----------------
__global__ __launch_bounds__(128, 2)
void k_g2(const ushortT* __restrict__ vb, const ushortT* __restrict__ WnT,
          ushortT* __restrict__ outH, int N, int segTiles){
  int tid = threadIdx.x;
  int wave = tid >> 6, lane = tid & 63;
  int m = lane & 15, quad = lane >> 4;
  int ntiles = (N + 15) >> 4;
  int xcd = blockIdx.x & (NXCD - 1);
  int idx = blockIdx.x >> 3;
  int wjIdx = idx * 2 + wave;
  int segWJ = segTiles >> 1;
  if (wjIdx >= segWJ) return;
  int t0 = xcd * segTiles + wjIdx * 2;
  if (t0 >= ntiles) return;

  bf16x8 av[2][4];
  #pragma unroll
  for (int rt = 0; rt < 2; ++rt){
    int row = (t0 + rt) * 16 + m; if (row >= N) row = N - 1;
    #pragma unroll
    for (int kk = 0; kk < 4; ++kk)
      av[rt][kk] = *(const bf16x8*)(vb + ((size_t)row << 7) + kk*32 + quad*8);
  }
  #pragma unroll
  for (int ct = 0; ct < 8; ++ct){
    int ncol = ct * 16 + m;
    const ushortT* bp = WnT + ((size_t)ncol << 7) + quad*8;
    bf16x8 bb[4];
    #pragma unroll
    for (int kk = 0; kk < 4; ++kk) bb[kk] = *(const bf16x8*)(bp + kk*32);
    #pragma unroll
    for (int rt = 0; rt < 2; ++rt){
      f32x4 d = mfma4r(av[rt], bb);
      #pragma unroll
      for (int r = 0; r < 4; ++r){
        int orow = (t0 + rt) * 16 + quad*4 + r;
        if (orow < N) outH[((size_t)orow << 7) + ncol] = f2bf(d[r]);
      }
    }
  }
}

// ---------------- readout from vb: one wave per node (no block barrier) -------
__global__ __launch_bounds__(256, 8)
void k_read(const ushortT* __restrict__ vb,
            const float* __restrict__ W1, const float* __restrict__ b1,
            const float* __restrict__ W2, const float* __restrict__ b2,
            float* __restrict__ u, int N, int segNodes){
  __shared__ float vbuf[4][HDIM];
  int xcd = blockIdx.x & (NXCD - 1);
  int idx = blockIdx.x >> 3;
  int wave = threadIdx.x >> 6, lane = threadIdx.x & 63;
  int node = xcd * segNodes + idx * 4 + wave;
  if (node >= N || node >= (xcd + 1) * segNodes) return;
  int f = lane * 2;
  unsigned int hh = *(const unsigned int*)(vb + ((size_t)node << 7) + f);
  vbuf[wave][f]     = bf2f((ushortT)hh);
  vbuf[wave][f + 1] = bf2f((ushortT)(hh >> 16));
  // wave-local LDS write->read; compiler orders via lgkmcnt
  float t0 = b1[lane], t1 = 0.f;
  #pragma unroll 8
  for (int k = 0; k < HDIM; k += 2){
    t0 = fmaf(vbuf[wave][k],     W1[k * 64 + lane],       t0);
    t1 = fmaf(vbuf[wave][k + 1], W1[(k + 1) * 64 + lane], t1);
  }
  float partial = ssp(t0 + t1) * W2[lane];
  #pragma unroll
  for (int off = 32; off > 0; off >>= 1)
    partial += __shfl_down(partial, off, 64);
  if (lane == 0) u[node] = partial + b2[0];
}

// ---------------- group segment sum over sorted batch ----------------
__global__ void k_gsum(const float* __restrict__ u, const int* __restrict__ groupOff,
                       float* __restrict__ out, int G){
  int g = blockIdx.x * 4 + (threadIdx.x >> 6);
  if (g >= G) return;
  int lane = threadIdx.x & 63;
  int s = groupOff[g], e = groupOff[g + 1];
  float acc = 0.f;
  for (int j = s + lane; j < e; j += 64) acc += u[j];
  #pragma unroll
  for (int off = 32; off > 0; off >>= 1)
    acc += __shfl_down(acc, off, 64);
  if (lane == 0) out[g] = acc;
}

extern "C" void kernel_launch(void* const* d_in, const int* in_sizes, int n_in,
                              void* d_out, int out_size, void* d_ws, size_t ws_size,
                              hipStream_t stream){
  const int N = in_sizes[0];
  const int E = in_sizes[3] / 2;
  const int G = out_size;

  const int*   z     = (const int*)d_in[0];
  const float* pos   = (const float*)d_in[1];
  const int*   batch = (const int*)d_in[2];
  const int*   eidx  = (const int*)d_in[3];
  const int*   erow  = eidx;
  const int*   ecol  = eidx + E;
  const float* emb   = (const float*)d_in[4];
  const float* dW    = (const float*)d_in[5];
  const float* db    = (const float*)d_in[6];
  const float* Wn    = (const float*)d_in[7];
  const float* We    = (const float*)d_in[8];
  const float* be    = (const float*)d_in[9];
  const float* Wo    = (const float*)d_in[10];
  const float* bo    = (const float*)d_in[11];
  const float* W1    = (const float*)d_in[12];
  const float* b1    = (const float*)d_in[13];
  const float* W2    = (const float*)d_in[14];
  const float* b2    = (const float*)d_in[15];

  char* ws = (char*)d_ws;
  size_t off = 0;
  auto alloc = [&](size_t bytes) -> char* {
    char* p = ws + off;
    off = (off + bytes + 255) & ~(size_t)255;
    return p;
  };
  int nscanb = (N + 255) / 256;
  int*          counts   = (int*)         alloc((size_t)N * 4);
  int*          offsets  = (int*)         alloc((size_t)(N + 1) * 4);
  int*          cursor   = (int*)         alloc((size_t)N * 4);
  int*          blockSums= (int*)         alloc((size_t)nscanb * 4);
  unsigned int* csr      = (unsigned int*)alloc((size_t)E * 4);
  ushortT*      h0       = (ushortT*)     alloc((size_t)N * HDIM * 2);
  ushortT*      h1       = (ushortT*)     alloc((size_t)N * HDIM * 2);
  ushortT*      vhi      = (ushortT*)     alloc((size_t)N * HDIM * 2);
  ushortT*      agghi    = (ushortT*)     alloc((size_t)N * HDIM * 2);
  ushortT*      vb       = (ushortT*)     alloc((size_t)N * HDIM * 2);
  ushortT*      WnT      = (ushortT*)     alloc((size_t)NLAYER * HDIM * HDIM * 2);
  ushortT*      WoT      = (ushortT*)     alloc((size_t)NLAYER * HDIM * HDIM * 2);
  float*        a        = (float*)       alloc((size_t)NLAYER * HDIM * 4);
  float*        c        = (float*)       alloc((size_t)NLAYER * HDIM * 4);
  float*        u        = (float*)       alloc((size_t)N * 4);
  int*          groupOff = (int*)         alloc((size_t)(G + 1) * 4);

  hipMemsetAsync(counts, 0, (size_t)N * 4, stream);

  int B1 = (N * HDIM + 255) / 256;
  int B2 = (NLAYER * HDIM * HDIM + 255) / 256;
  int B4 = (NLAYER * HDIM + 255) / 256;
  int B5 = (N + 255) / 256;
  int B6 = (E + 255) / 256;
  k_setup<<<B1 + 2*B2 + B4 + B5 + B6, 256, 0, stream>>>(
      z, emb, vhi, Wn, WnT, Wo, WoT,
      dW, db, We, be, a, c, batch, groupOff, erow, counts,
      N, E, G, B1, B2, B4, B5, B6);

  k_scan1<<<nscanb, 256, 0, stream>>>(counts, blockSums, N);
  k_scan3<<<nscanb, 256, 0, stream>>>(counts, blockSums, offsets, cursor, N, nscanb);
  k_fill<<<(E + 255) / 256, 256, 0, stream>>>(erow, ecol, pos, cursor, csr, E);

  int ntiles = (N + 15) >> 4;
  int segTiles = (((ntiles + NXCD - 1) / NXCD) + 1) & ~1;   // even tiles/XCD
  int segNodes = segTiles * 16;
  int segWJ = segTiles >> 1;
  int aggGrid  = NXCD * ((segNodes + 3) / 4);
  int gGrid    = NXCD * ((segWJ + 1) / 2);
  int nwj = (ntiles + 1) / 2;
  int pairGrid = (nwj + 1) / 2;
  k_gemm0<<<pairGrid, 128, 0, stream>>>(vhi, WnT, h0, N);

  for (int l = 0; l < NLAYER; ++l){
    size_t wo = (size_t)l * HDIM * HDIM;
    const ushortT* hin  = (l & 1) ? h1 : h0;
    ushortT*       hout = (l & 1) ? h0 : h1;
    k_agg2<<<aggGrid, 256, 0, stream>>>(hin, offsets, csr,
                                        a + l * HDIM, c + l * HDIM, agghi, N, segNodes);
    k_g1<<<gGrid, 128, 0, stream>>>(agghi, WoT + wo, bo + (size_t)l * HDIM,
                                    vb, N, segTiles);
    if (l < NLAYER - 1){
      size_t wn = (size_t)(l + 1) * HDIM * HDIM;
      k_g2<<<gGrid, 128, 0, stream>>>(vb, WnT + wn, hout, N, segTiles);
    } else {
      k_read<<<aggGrid, 256, 0, stream>>>(vb, W1, b1, W2, b2, u, N, segNodes);
    }
  }
  k_gsum<<<(G + 3) / 4, 256, 0, stream>>>(u, groupOff, (float*)d_out, G);
}

// Round 19
// 793.678 us; speedup vs baseline: 2.2476x; 1.0180x over previous
//
#include <hip/hip_runtime.h>
#include <math.h>

#define HDIM 128
#define NGAUSS 50
#define NLAYER 6
#define TSTR 136   // LDS bf16 tile row stride (shorts); %8==0 keeps ds_read_b128 aligned
#define DINV (1.0f/512.0f)
#define NXCD 8

typedef unsigned short ushortT;
typedef __attribute__((ext_vector_type(8))) short bf16x8;
typedef __attribute__((ext_vector_type(4))) float f32x4;

static __device__ __forceinline__ float bf2f(unsigned short u){
  union { unsigned int i; float f; } x; x.i = ((unsigned int)u) << 16; return x.f;
}
static __device__ __forceinline__ unsigned short f2bf(float f){
  union { float f; unsigned int i; } x; x.f = f;
  unsigned int i = x.i;
  unsigned int r = (i + 0x7FFFu + ((i >> 16) & 1u)) >> 16;
  return (unsigned short)r;
}
static __device__ __forceinline__ float ssp(float x){
  return fmaxf(x, 0.0f) + __logf(1.0f + __expf(-fabsf(x))) - 0.69314718055994530942f;
}
static __device__ __forceinline__ f32x4 mfma4r(const bf16x8* a, const bf16x8* b){
  f32x4 d = {0.f, 0.f, 0.f, 0.f};
  d = __builtin_amdgcn_mfma_f32_16x16x32_bf16(a[0], b[0], d, 0, 0, 0);
  d = __builtin_amdgcn_mfma_f32_16x16x32_bf16(a[1], b[1], d, 0, 0, 0);
  d = __builtin_amdgcn_mfma_f32_16x16x32_bf16(a[2], b[2], d, 0, 0, 0);
  d = __builtin_amdgcn_mfma_f32_16x16x32_bf16(a[3], b[3], d, 0, 0, 0);
  return d;
}

// ---------------- scans ----------------
__global__ void k_scan1(const int* __restrict__ counts, int* __restrict__ blockSums, int N){
  __shared__ int red[256];
  int tid = threadIdx.x;
  int i = blockIdx.x * 256 + tid;
  red[tid] = (i < N) ? counts[i] : 0;
  __syncthreads();
  #pragma unroll
  for (int off = 128; off > 0; off >>= 1){
    if (tid < off) red[tid] += red[tid + off];
    __syncthreads();
  }
  if (tid == 0) blockSums[blockIdx.x] = red[0];
}

__global__ void k_scan3(const int* __restrict__ counts, const int* __restrict__ blockSums,
                        int* __restrict__ offsets, int* __restrict__ cursor, int N, int nb){
  __shared__ int bs[256];
  __shared__ int s[256];
  int tid = threadIdx.x;
  bs[tid] = (tid < nb) ? blockSums[tid] : 0;
  __syncthreads();
  #pragma unroll
  for (int off = 1; off < 256; off <<= 1){
    int t = (tid >= off) ? bs[tid - off] : 0;
    __syncthreads();
    bs[tid] += t;
    __syncthreads();
  }
  int myOff = (blockIdx.x == 0) ? 0 : bs[blockIdx.x - 1];
  int i = blockIdx.x * 256 + tid;
  int v = (i < N) ? counts[i] : 0;
  s[tid] = v;
  __syncthreads();
  #pragma unroll
  for (int off = 1; off < 256; off <<= 1){
    int t = (tid >= off) ? s[tid - off] : 0;
    __syncthreads();
    s[tid] += t;
    __syncthreads();
  }
  int excl = myOff + s[tid] - v;
  if (i < N){ offsets[i] = excl; cursor[i] = excl; }
  if (i == N - 1) offsets[N] = excl + v;
}

// csr record: col<<16 | round(dist*512), stored via device-scope atomicExch so
// same-line records from different XCDs merge at the coherent level (kills the
// 16x partial-line writeback amplification of plain scattered 4B stores).
__global__ void k_fill(const int* __restrict__ row, const int* __restrict__ col,
                       const float* __restrict__ pos, int* __restrict__ cursor,
                       unsigned int* __restrict__ csr, int E){
  int e = blockIdx.x * 256 + threadIdx.x;
  if (e >= E) return;
  int r = row[e], c = col[e];
  float dx = pos[r*3+0] - pos[c*3+0];
  float dy = pos[r*3+1] - pos[c*3+1];
  float dz = pos[r*3+2] - pos[c*3+2];
  float d = sqrtf(dx*dx + dy*dy + dz*dz);
  int du = (int)(d * 512.0f + 0.5f);
  if (du > 65535) du = 65535;
  int slot = atomicAdd(&cursor[r], 1);
  atomicExch(&csr[slot], ((unsigned int)c << 16) | (unsigned int)du);
}

// ---------------- merged setup (+ degree count; counts pre-zeroed by memset) ---
__global__ void k_setup(const int* __restrict__ z, const float* __restrict__ emb,
                        ushortT* __restrict__ vhi,
                        const float* __restrict__ Wn, ushortT* __restrict__ WnT,
                        const float* __restrict__ Wo, ushortT* __restrict__ WoT,
                        const float* __restrict__ dW, const float* __restrict__ db,
                        const float* __restrict__ We, const float* __restrict__ be,
                        float* __restrict__ a, float* __restrict__ c,
                        const int* __restrict__ batch, int* __restrict__ groupOff,
                        const int* __restrict__ erow, int* __restrict__ counts,
                        int N, int E, int G, int B1, int B2, int B4, int B5, int B6){
  int b = blockIdx.x;
  int tid = threadIdx.x;
  if (b < B1){
    int idx = b * 256 + tid;
    if (idx < N * HDIM){
      int n = idx >> 7, f = idx & 127;
      vhi[idx] = f2bf(emb[z[n] * HDIM + f]);
    }
    return;
  }
  b -= B1;
  if (b < B2){
    int idx = b * 256 + tid;
    if (idx < NLAYER * HDIM * HDIM){
      int mat = idx >> 14, rem = idx & 16383;
      int n = rem >> 7, k = rem & 127;
      WnT[idx] = f2bf(Wn[(mat << 14) + k * HDIM + n]);
    }
    return;
  }
  b -= B2;
  if (b < B2){
    int idx = b * 256 + tid;
    if (idx < NLAYER * HDIM * HDIM){
      int mat = idx >> 14, rem = idx & 16383;
      int n = rem >> 7, k = rem & 127;
      WoT[idx] = f2bf(Wo[(mat << 14) + k * HDIM + n]);
    }
    return;
  }
  b -= B2;
  if (b < B4){
    int idx = b * 256 + tid;
    if (idx < NLAYER * HDIM){
      int l = idx >> 7, f = idx & 127;
      float av = 0.f, cv = 0.f;
      for (int g = 0; g < NGAUSS; ++g){
        float we = We[(l * NGAUSS + g) * HDIM + f];
        av += dW[g] * we;
        cv += db[g] * we;
      }
      a[idx] = av;
      c[idx] = cv + be[idx];
    }
    return;
  }
  b -= B4;
  if (b < B5){
    int i = b * 256 + tid;
    if (i >= N) return;
    int bb = batch[i];
    if (i == 0){
      for (int g = 0; g <= bb; ++g) groupOff[g] = 0;
    } else {
      int pb = batch[i - 1];
      for (int g = pb + 1; g <= bb; ++g) groupOff[g] = i;
    }
    if (i == N - 1){
      for (int g = bb + 1; g <= G; ++g) groupOff[g] = N;
    }
    return;
  }
  b -= B5;
  if (b < B6){
    int e = b * 256 + tid;
    if (e < E) atomicAdd(&counts[erow[e]], 1);
  }
}

// ---------------- initial GEMM: h0 = v0 @ Wn[0]; 2 row-tiles per wave ----------
__global__ __launch_bounds__(128, 2)
void k_gemm0(const ushortT* __restrict__ X, const ushortT* __restrict__ WT,
             ushortT* __restrict__ outHi, int N){
  int tid = threadIdx.x;
  int wave = tid >> 6, lane = tid & 63;
  int m = lane & 15, quad = lane >> 4;
  int ntiles = (N + 15) >> 4;
  int t0 = (blockIdx.x * 2 + wave) * 2;
  if (t0 >= ntiles) return;

  bf16x8 av[2][4];
  #pragma unroll
  for (int rt = 0; rt < 2; ++rt){
    int row = (t0 + rt) * 16 + m; if (row >= N) row = N - 1;
    #pragma unroll
    for (int kk = 0; kk < 4; ++kk)
      av[rt][kk] = *(const bf16x8*)(X + ((size_t)row << 7) + kk*32 + quad*8);
  }
  #pragma unroll
  for (int ct = 0; ct < 8; ++ct){
    int ncol = ct * 16 + m;
    const ushortT* bp = WT + ((size_t)ncol << 7) + quad*8;
    bf16x8 bb[4];
    #pragma unroll
    for (int kk = 0; kk < 4; ++kk) bb[kk] = *(const bf16x8*)(bp + kk*32);
    #pragma unroll
    for (int rt = 0; rt < 2; ++rt){
      f32x4 d = mfma4r(av[rt], bb);
      #pragma unroll
      for (int r = 0; r < 4; ++r){
        int orow = (t0 + rt) * 16 + quad*4 + r;
        if (orow < N) outHi[((size_t)orow << 7) + ncol] = f2bf(d[r]);
      }
    }
  }
}

// ---------------- edge aggregation, XCD-swizzled node ownership ----------------
__global__ __launch_bounds__(256, 8)
void k_agg2(const ushortT* __restrict__ h, const int* __restrict__ offsets,
            const unsigned int* __restrict__ cd, const float* __restrict__ a,
            const float* __restrict__ c, ushortT* __restrict__ aggHi,
            int N, int segNodes){
  int xcd = blockIdx.x & (NXCD - 1);
  int idx = blockIdx.x >> 3;
  int node = xcd * segNodes + idx * 4 + (threadIdx.x >> 6);
  if (node >= N || node >= (xcd + 1) * segNodes) return;
  int lane = threadIdx.x & 63;
  int half = lane >> 5;
  int fl = (lane & 31) * 4;
  float4 av = *(const float4*)(a + fl);
  float4 cv = *(const float4*)(c + fl);
  int s = offsets[node], e = offsets[node + 1];
  float acc0 = 0.f, acc1 = 0.f, acc2 = 0.f, acc3 = 0.f;
  int j = s;
  for (; j + 8 <= e; j += 8){
    unsigned int q[4]; uint2 p[4];
    #pragma unroll
    for (int i = 0; i < 4; ++i) q[i] = cd[j + 2*i + half];
    #pragma unroll
    for (int i = 0; i < 4; ++i)
      p[i] = *(const uint2*)(h + ((size_t)(q[i] >> 16) << 7) + fl);
    #pragma unroll
    for (int i = 0; i < 4; ++i){
      float dd = (float)(q[i] & 0xFFFFu) * DINV;
      acc0 = fmaf(bf2f((ushortT)p[i].x),         fmaf(dd, av.x, cv.x), acc0);
      acc1 = fmaf(bf2f((ushortT)(p[i].x >> 16)), fmaf(dd, av.y, cv.y), acc1);
      acc2 = fmaf(bf2f((ushortT)p[i].y),         fmaf(dd, av.z, cv.z), acc2);
      acc3 = fmaf(bf2f((ushortT)(p[i].y >> 16)), fmaf(dd, av.w, cv.w), acc3);
    }
  }
  for (; j < e; j += 2){
    int myj = j + half;
    if (myj < e){
      unsigned int q = cd[myj];
      uint2 p = *(const uint2*)(h + ((size_t)(q >> 16) << 7) + fl);
      float dd = (float)(q & 0xFFFFu) * DINV;
      acc0 = fmaf(bf2f((ushortT)p.x),         fmaf(dd, av.x, cv.x), acc0);
      acc1 = fmaf(bf2f((ushortT)(p.x >> 16)), fmaf(dd, av.y, cv.y), acc1);
      acc2 = fmaf(bf2f((ushortT)p.y),         fmaf(dd, av.z, cv.z), acc2);
      acc3 = fmaf(bf2f((ushortT)(p.y >> 16)), fmaf(dd, av.w, cv.w), acc3);
    }
  }
  acc0 += __shfl_down(acc0, 32, 64);
  acc1 += __shfl_down(acc1, 32, 64);
  acc2 += __shfl_down(acc2, 32, 64);
  acc3 += __shfl_down(acc3, 32, 64);
  if (half == 0){
    uint2 ph;
    ph.x = (unsigned int)f2bf(acc0) | ((unsigned int)f2bf(acc1) << 16);
    ph.y = (unsigned int)f2bf(acc2) | ((unsigned int)f2bf(acc3) << 16);
    *(uint2*)(aggHi + ((size_t)node << 7) + fl) = ph;
  }
}

// ---------------- fused GEMM pair, wave-private LDS, no barrier ----------------
// 128 threads = 2 waves; each wave owns 2 row-tiles. v = ssp(agg@Wo+bo) goes to
// the wave's private LDS tile (same-wave lgkmcnt ordering, no __syncthreads),
// then h' = v @ WnNext. XCD-swizzled tile segments match k_agg2's writer map.
__global__ __launch_bounds__(128, 2)
void k_fpair(const ushortT* __restrict__ agg, const ushortT* __restrict__ WoT,
             const float* __restrict__ bo, const ushortT* __restrict__ WnT,
             ushortT* __restrict__ outH, int N, int segTiles){
  __shared__ ushortT vt[2][32 * TSTR];
  int tid = threadIdx.x;
  int wave = tid >> 6, lane = tid & 63;
  int m = lane & 15, quad = lane >> 4;
  int ntiles = (N + 15) >> 4;
  int xcd = blockIdx.x & (NXCD - 1);
  int idx = blockIdx.x >> 3;
  int wjIdx = idx * 2 + wave;
  int segWJ = segTiles >> 1;
  if (wjIdx >= segWJ) return;
  int t0 = xcd * segTiles + wjIdx * 2;
  if (t0 >= ntiles) return;
  ushortT* vw = vt[wave];

  // GEMM1: v = ssp(agg @ Wo + bo) -> wave-private LDS
  bf16x8 av[2][4];
  #pragma unroll
  for (int rt = 0; rt < 2; ++rt){
    int row = (t0 + rt) * 16 + m; if (row >= N) row = N - 1;
    #pragma unroll
    for (int kk = 0; kk < 4; ++kk)
      av[rt][kk] = *(const bf16x8*)(agg + ((size_t)row << 7) + kk*32 + quad*8);
  }
  #pragma unroll
  for (int ct = 0; ct < 8; ++ct){
    int ncol = ct * 16 + m;
    const ushortT* bp = WoT + ((size_t)ncol << 7) + quad*8;
    bf16x8 bb[4];
    #pragma unroll
    for (int kk = 0; kk < 4; ++kk) bb[kk] = *(const bf16x8*)(bp + kk*32);
    float bbias = bo[ncol];
    #pragma unroll
    for (int rt = 0; rt < 2; ++rt){
      f32x4 d = mfma4r(av[rt], bb);
      #pragma unroll
      for (int r = 0; r < 4; ++r)
        vw[(rt*16 + quad*4 + r) * TSTR + ncol] = f2bf(ssp(d[r] + bbias));
    }
  }
  // GEMM2: h' = v @ WnNext (same-wave ds_write->ds_read, lgkmcnt-ordered)
  bf16x8 a2[2][4];
  #pragma unroll
  for (int rt = 0; rt < 2; ++rt){
    #pragma unroll
    for (int kk = 0; kk < 4; ++kk)
      a2[rt][kk] = *(const bf16x8*)(&vw[(rt*16 + m) * TSTR + kk*32 + quad*8]);
  }
  #pragma unroll
  for (int ct = 0; ct < 8; ++ct){
    int ncol = ct * 16 + m;
    const ushortT* bp = WnT + ((size_t)ncol << 7) + quad*8;
    bf16x8 bb[4];
    #pragma unroll
    for (int kk = 0; kk < 4; ++kk) bb[kk] = *(const bf16x8*)(bp + kk*32);
    #pragma unroll
    for (int rt = 0; rt < 2; ++rt){
      f32x4 d = mfma4r(a2[rt], bb);
      #pragma unroll
      for (int r = 0; r < 4; ++r){
        int orow = (t0 + rt) * 16 + quad*4 + r;
        if (orow < N) outH[((size_t)orow << 7) + ncol] = f2bf(d[r]);
      }
    }
  }
}

// ---------------- last-layer GEMM 1: v = ssp(agg @ Wo + bo) -> vb (bf16) ------
__global__ __launch_bounds__(128, 2)
void k_g1(const ushortT* __restrict__ agg, const ushortT* __restrict__ WoT,
          const float* __restrict__ bo, ushortT* __restrict__ vb,
          int N, int segTiles){
  int tid = threadIdx.x;
  int wave = tid >> 6, lane = tid & 63;
  int m = lane & 15, quad = lane >> 4;
  int ntiles = (N + 15) >> 4;
  int xcd = blockIdx.x & (NXCD - 1);
  int idx = blockIdx.x >> 3;
  int wjIdx = idx * 2 + wave;
  int segWJ = segTiles >> 1;
  if (wjIdx >= segWJ) return;
  int t0 = xcd * segTiles + wjIdx * 2;
  if (t0 >= ntiles) return;

  bf16x8 av[2][4];
  #pragma unroll
  for (int rt = 0; rt < 2; ++rt){
    int row = (t0 + rt) * 16 + m; if (row >= N) row = N - 1;
    #pragma unroll
    for (int kk = 0; kk < 4; ++kk)
      av[rt][kk] = *(const bf16x8*)(agg + ((size_t)row << 7) + kk*32 + quad*8);
  }
  #pragma unroll
  for (int ct = 0; ct < 8; ++ct){
    int ncol = ct * 16 + m;
    const ushortT* bp = WoT + ((size_t)ncol << 7) + quad*8;
    bf16x8 bb[4];
    #pragma unroll
    for (int kk = 0; kk < 4; ++kk) bb[kk] = *(const bf16x8*)(bp + kk*32);
    float bbias = bo[ncol];
    #pragma unroll
    for (int rt = 0; rt < 2; ++rt){
      f32x4 d = mfma4r(av[rt], bb);
      #pragma unroll
      for (int r = 0; r < 4; ++r){
        int orow = (t0 + rt) * 16 + quad*4 + r;
        if (orow < N) vb[((size_t)orow << 7) + ncol] = f2bf(ssp(d[r] + bbias));
      }
    }
  }
}

// ---------------- readout from vb: one wave per node ----------------
__global__ __launch_bounds__(256, 8)
void k_read(const ushortT* __restrict__ vb,
            const float* __restrict__ W1, const float* __restrict__ b1,
            const float* __restrict__ W2, const float* __restrict__ b2,
            float* __restrict__ u, int N, int segNodes){
  __shared__ float vbuf[4][HDIM];
  int xcd = blockIdx.x & (NXCD - 1);
  int idx = blockIdx.x >> 3;
  int wave = threadIdx.x >> 6, lane = threadIdx.x & 63;
  int node = xcd * segNodes + idx * 4 + wave;
  if (node >= N || node >= (xcd + 1) * segNodes) return;
  int f = lane * 2;
  unsigned int hh = *(const unsigned int*)(vb + ((size_t)node << 7) + f);
  vbuf[wave][f]     = bf2f((ushortT)hh);
  vbuf[wave][f + 1] = bf2f((ushortT)(hh >> 16));
  float t0 = b1[lane], t1 = 0.f;
  #pragma unroll 8
  for (int k = 0; k < HDIM; k += 2){
    t0 = fmaf(vbuf[wave][k],     W1[k * 64 + lane],       t0);
    t1 = fmaf(vbuf[wave][k + 1], W1[(k + 1) * 64 + lane], t1);
  }
  float partial = ssp(t0 + t1) * W2[lane];
  #pragma unroll
  for (int off = 32; off > 0; off >>= 1)
    partial += __shfl_down(partial, off, 64);
  if (lane == 0) u[node] = partial + b2[0];
}

// ---------------- group segment sum over sorted batch ----------------
__global__ void k_gsum(const float* __restrict__ u, const int* __restrict__ groupOff,
                       float* __restrict__ out, int G){
  int g = blockIdx.x * 4 + (threadIdx.x >> 6);
  if (g >= G) return;
  int lane = threadIdx.x & 63;
  int s = groupOff[g], e = groupOff[g + 1];
  float acc = 0.f;
  for (int j = s + lane; j < e; j += 64) acc += u[j];
  #pragma unroll
  for (int off = 32; off > 0; off >>= 1)
    acc += __shfl_down(acc, off, 64);
  if (lane == 0) out[g] = acc;
}

extern "C" void kernel_launch(void* const* d_in, const int* in_sizes, int n_in,
                              void* d_out, int out_size, void* d_ws, size_t ws_size,
                              hipStream_t stream){
  const int N = in_sizes[0];
  const int E = in_sizes[3] / 2;
  const int G = out_size;

  const int*   z     = (const int*)d_in[0];
  const float* pos   = (const float*)d_in[1];
  const int*   batch = (const int*)d_in[2];
  const int*   eidx  = (const int*)d_in[3];
  const int*   erow  = eidx;
  const int*   ecol  = eidx + E;
  const float* emb   = (const float*)d_in[4];
  const float* dW    = (const float*)d_in[5];
  const float* db    = (const float*)d_in[6];
  const float* Wn    = (const float*)d_in[7];
  const float* We    = (const float*)d_in[8];
  const float* be    = (const float*)d_in[9];
  const float* Wo    = (const float*)d_in[10];
  const float* bo    = (const float*)d_in[11];
  const float* W1    = (const float*)d_in[12];
  const float* b1    = (const float*)d_in[13];
  const float* W2    = (const float*)d_in[14];
  const float* b2    = (const float*)d_in[15];

  char* ws = (char*)d_ws;
  size_t off = 0;
  auto alloc = [&](size_t bytes) -> char* {
    char* p = ws + off;
    off = (off + bytes + 255) & ~(size_t)255;
    return p;
  };
  int nscanb = (N + 255) / 256;
  int*          counts   = (int*)         alloc((size_t)N * 4);
  int*          offsets  = (int*)         alloc((size_t)(N + 1) * 4);
  int*          cursor   = (int*)         alloc((size_t)N * 4);
  int*          blockSums= (int*)         alloc((size_t)nscanb * 4);
  unsigned int* csr      = (unsigned int*)alloc((size_t)E * 4);
  ushortT*      h0       = (ushortT*)     alloc((size_t)N * HDIM * 2);
  ushortT*      h1       = (ushortT*)     alloc((size_t)N * HDIM * 2);
  ushortT*      vhi      = (ushortT*)     alloc((size_t)N * HDIM * 2);
  ushortT*      agghi    = (ushortT*)     alloc((size_t)N * HDIM * 2);
  ushortT*      vb       = (ushortT*)     alloc((size_t)N * HDIM * 2);
  ushortT*      WnT      = (ushortT*)     alloc((size_t)NLAYER * HDIM * HDIM * 2);
  ushortT*      WoT      = (ushortT*)     alloc((size_t)NLAYER * HDIM * HDIM * 2);
  float*        a        = (float*)       alloc((size_t)NLAYER * HDIM * 4);
  float*        c        = (float*)       alloc((size_t)NLAYER * HDIM * 4);
  float*        u        = (float*)       alloc((size_t)N * 4);
  int*          groupOff = (int*)         alloc((size_t)(G + 1) * 4);

  hipMemsetAsync(counts, 0, (size_t)N * 4, stream);

  int B1 = (N * HDIM + 255) / 256;
  int B2 = (NLAYER * HDIM * HDIM + 255) / 256;
  int B4 = (NLAYER * HDIM + 255) / 256;
  int B5 = (N + 255) / 256;
  int B6 = (E + 255) / 256;
  k_setup<<<B1 + 2*B2 + B4 + B5 + B6, 256, 0, stream>>>(
      z, emb, vhi, Wn, WnT, Wo, WoT,
      dW, db, We, be, a, c, batch, groupOff, erow, counts,
      N, E, G, B1, B2, B4, B5, B6);

  k_scan1<<<nscanb, 256, 0, stream>>>(counts, blockSums, N);
  k_scan3<<<nscanb, 256, 0, stream>>>(counts, blockSums, offsets, cursor, N, nscanb);
  k_fill<<<(E + 255) / 256, 256, 0, stream>>>(erow, ecol, pos, cursor, csr, E);

  int ntiles = (N + 15) >> 4;
  int segTiles = (((ntiles + NXCD - 1) / NXCD) + 1) & ~1;   // even tiles/XCD
  int segNodes = segTiles * 16;
  int segWJ = segTiles >> 1;
  int aggGrid  = NXCD * ((segNodes + 3) / 4);
  int gGrid    = NXCD * ((segWJ + 1) / 2);
  int nwj = (ntiles + 1) / 2;
  int pairGrid = (nwj + 1) / 2;
  k_gemm0<<<pairGrid, 128, 0, stream>>>(vhi, WnT, h0, N);

  for (int l = 0; l < NLAYER; ++l){
    size_t wo = (size_t)l * HDIM * HDIM;
    const ushortT* hin  = (l & 1) ? h1 : h0;
    ushortT*       hout = (l & 1) ? h0 : h1;
    k_agg2<<<aggGrid, 256, 0, stream>>>(hin, offsets, csr,
                                        a + l * HDIM, c + l * HDIM, agghi, N, segNodes);
    if (l < NLAYER - 1){
      size_t wn = (size_t)(l + 1) * HDIM * HDIM;
      k_fpair<<<gGrid, 128, 0, stream>>>(agghi, WoT + wo, bo + (size_t)l * HDIM,
                                         WnT + wn, hout, N, segTiles);
    } else {
      k_g1<<<gGrid, 128, 0, stream>>>(agghi, WoT + wo, bo + (size_t)l * HDIM,
                                      vb, N, segTiles);
      k_read<<<aggGrid, 256, 0, stream>>>(vb, W1, b1, W2, b2, u, N, segNodes);
    }
  }
  k_gsum<<<(G + 3) / 4, 256, 0, stream>>>(u, groupOff, (float*)d_out, G);
}